// Round 5
// baseline (1234.830 us; speedup 1.0000x reference)
//
#include <hip/hip_runtime.h>

#define VOCAB 28996
#define BB 32
#define SS 512
#define DD 768
#define NCLS 9
#define ROWS (BB*SS)     // 16384
#define IN2 (2*DD)       // 1536
#define G4 (4*DD)        // 3072
#define NB2 (2*G4)       // 6144

typedef __attribute__((ext_vector_type(8))) short short8;
typedef __attribute__((ext_vector_type(4))) short shortx4;
typedef __attribute__((ext_vector_type(4))) float floatx4;
typedef unsigned long long ull;

__device__ __forceinline__ float bf2f(unsigned short u){
  union { unsigned int i; float f; } v; v.i = ((unsigned int)u) << 16; return v.f;
}
__device__ __forceinline__ unsigned short f2bf(float f){
  union { float f; unsigned int i; } v; v.f = f;
  unsigned int r = v.i + 0x7FFFu + ((v.i >> 16) & 1u);
  return (unsigned short)(r >> 16);
}
__device__ __forceinline__ float sigf(float x){ return 1.0f / (1.0f + __expf(-x)); }
__device__ __forceinline__ float tanhfast(float x){
  float y = fminf(fmaxf(x, -15.f), 15.f);
  float e = __expf(2.f * y);
  return 1.f - 2.f / (e + 1.f);
}

__device__ __forceinline__ void gl_lds16(const unsigned short* g, unsigned short* l){
  __builtin_amdgcn_global_load_lds((__attribute__((address_space(1))) void*)(g),
                                   (__attribute__((address_space(3))) void*)(l), 16, 0, 0);
}
// coherent variant: sc0|sc1 -> bypass L1+L2, read memory-side L3 (h path only)
__device__ __forceinline__ void gl_lds16_c(const unsigned short* g, unsigned short* l){
  __builtin_amdgcn_global_load_lds((__attribute__((address_space(1))) void*)(g),
                                   (__attribute__((address_space(3))) void*)(l), 16, 0, 17);
}
// write-through store to the coherence point (L3) so sc1 readers on other XCDs see it
__device__ __forceinline__ void store16_sc1(unsigned short* p, short8 v){
  asm volatile("global_store_dwordx4 %0, %1, off sc0 sc1" :: "v"(p), "v"(v) : "memory");
}

#define VMCNT(n) do { asm volatile("s_waitcnt vmcnt(" #n ")" ::: "memory"); \
                      __builtin_amdgcn_sched_barrier(0); } while (0)

// ---------------- segment mean ----------------
__global__ void seg_scatter(const int* __restrict__ ids, const float* __restrict__ hidden,
                            float* __restrict__ sums, float* __restrict__ counts)
{
  int r = blockIdx.x;
  int id = ids[r];
  const float* h = hidden + (long)r * DD;
  float* s = sums + (long)id * DD;
  for (int d = threadIdx.x; d < DD; d += 256)
    atomicAdd(&s[d], h[d]);
  if (threadIdx.x == 0) atomicAdd(&counts[id], 1.0f);
}

__global__ void build_x(const int* __restrict__ ids, const float* __restrict__ hidden,
                        const float* __restrict__ sums, const float* __restrict__ counts,
                        unsigned short* __restrict__ x)
{
  int r = blockIdx.x;
  int id = ids[r];
  float inv = 1.0f / fmaxf(counts[id], 1.0f);
  const float* h = hidden + (long)r * DD;
  const float* s = sums + (long)id * DD;
  unsigned short* xr = x + (long)r * IN2;
  for (int d = threadIdx.x; d < DD; d += 256) {
    xr[d]      = f2bf(h[d]);
    xr[DD + d] = f2bf(s[d] * inv);
  }
}

// -------- weight conversion with gate-interleave permutation: row' = u*4+g <- row g*768+u --------
__global__ void conv_w_perm(const float* __restrict__ w, unsigned short* __restrict__ o, int K)
{
  long i = (long)blockIdx.x * 256 + threadIdx.x;
  if (i >= (long)G4 * K) return;
  int row = (int)(i / K); int k = (int)(i - (long)row * K);
  int u = row >> 2, g = row & 3;
  o[i] = f2bf(w[((long)(g * DD + u)) * K + k]);
}

__global__ void conv_bias_perm(const float* __restrict__ bif, const float* __restrict__ bhf,
                               const float* __restrict__ bib, const float* __restrict__ bhb,
                               float* __restrict__ o)
{
  int n = blockIdx.x * 256 + threadIdx.x;
  if (n >= NB2) return;
  int d = n / G4, rr = n - d * G4, u = rr >> 2, g = rr & 3;
  int s = g * DD + u;
  o[n] = d ? (bib[s] + bhb[s]) : (bif[s] + bhf[s]);
}

// ---------------- GEMM: C[m,n] = sum_k A[m,k]*B[n,k] + bias[n], bf16 out ----------------
__global__ __launch_bounds__(256, 2)
void gemm_bt(const unsigned short* __restrict__ A, int lda,
             const unsigned short* __restrict__ B, int ldb,
             unsigned short* __restrict__ C, int ldc,
             const float* __restrict__ bias, int K)
{
  __shared__ unsigned short lA[128 * 32];
  __shared__ unsigned short lB[128 * 32];
  const int t = threadIdx.x;
  const int lane = t & 63;
  const int wv = t >> 6;
  const int wm = wv >> 1, wn = wv & 1;
  const int l15 = lane & 15, q = lane >> 4;
  const long m0 = (long)blockIdx.y * 128;
  const long n0 = (long)blockIdx.x * 128;
  const int rowS = t >> 2;
  const int kc = (((t & 3) ^ ((t >> 3) & 3))) * 8;         // swizzled source slot
  const int qsw = (q ^ ((l15 >> 1) & 3)) * 8;              // swizzled read slot
  const unsigned short* gA = A + (m0 + rowS) * lda + kc;
  const unsigned short* gB = B + (n0 + rowS) * ldb + kc;
  unsigned short* dA0 = lA + (wv << 9);
  unsigned short* dA1 = lA + 2048 + (wv << 9);
  unsigned short* dB0 = lB + (wv << 9);
  unsigned short* dB1 = lB + 2048 + (wv << 9);

  floatx4 acc[4][4];
  #pragma unroll
  for (int i = 0; i < 4; i++)
    #pragma unroll
    for (int j = 0; j < 4; j++)
      acc[i][j] = (floatx4){0.f, 0.f, 0.f, 0.f};

  const long a64 = (long)64 * lda;
  const long b64 = (long)64 * ldb;
  for (int kt = 0; kt < K; kt += 32) {
    gl_lds16(gA + kt,       dA0);
    gl_lds16(gA + a64 + kt, dA1);
    gl_lds16(gB + kt,       dB0);
    gl_lds16(gB + b64 + kt, dB1);
    __syncthreads();
    short8 af[4], bfr[4];
    #pragma unroll
    for (int i = 0; i < 4; i++)
      af[i] = *(const short8*)(lA + (wm * 64 + i * 16 + l15) * 32 + qsw);
    #pragma unroll
    for (int j = 0; j < 4; j++)
      bfr[j] = *(const short8*)(lB + (wn * 64 + j * 16 + l15) * 32 + qsw);
    #pragma unroll
    for (int i = 0; i < 4; i++)
      #pragma unroll
      for (int j = 0; j < 4; j++)
        acc[i][j] = __builtin_amdgcn_mfma_f32_16x16x32_bf16(af[i], bfr[j], acc[i][j], 0, 0, 0);
    __syncthreads();
  }

  #pragma unroll
  for (int i = 0; i < 4; i++) {
    #pragma unroll
    for (int j = 0; j < 4; j++) {
      const long mg = m0 + wm * 64 + i * 16 + q * 4;
      const long ng = n0 + wn * 64 + j * 16 + l15;
      const float bb = bias[ng];
      #pragma unroll
      for (int r = 0; r < 4; r++)
        C[(mg + r) * ldc + ng] = f2bf(acc[i][j][r] + bb);
    }
  }
}

// ---------------- persistent bidirectional LSTM recurrence ----------------
// 8 waves (2/SIMD). K=128 super-tiles (6/step), classic double-buffer with counted
// vmcnt (16/8/8/8/8/0 -- never 0 mid-loop): big scheduling windows (24 ds_read_b128
// + 64 MFMA) let the compiler deep-interleave with partial lgkmcnt. xg gate-tile in
// REGISTERS (8x8B/thread, T14) -- no xgs LDS buffer. setprio(1) around MFMA cluster
// (T5). Synchronization: R3-PROVEN generation barrier (thread-0 arrive/spin, raw
// s_barriers, single VMCNT(0) draining only the epilogue stores). sc1-coherent h
// path; transposed-MFMA zero-shuffle epilogue; XOR-swizzled LDS.
__global__ __launch_bounds__(512, 1)
void lstm_persist(const unsigned short* __restrict__ xg, int ldxg,
                  const unsigned short* __restrict__ whh,   // [2][3072][768] permuted
                  unsigned short* __restrict__ hbuf,        // [2][ndir][512][768]
                  unsigned short* __restrict__ outc,        // [16384][1536]
                  unsigned* bar,                            // 8 groups x 16 u32
                  int dir0, int ndir)
{
  __shared__ unsigned short bufA[2][16384];   // dbuf x 4 panels [128][32], swizzled
  __shared__ unsigned short bufB[2][16384];
  __shared__ unsigned short hout[128 * 40];   // h staging, pad 40

  const int bid = blockIdx.x;
  const int xcd = bid & 7;
  const int idx = bid >> 3;
  int dm, k3;
  if (ndir == 2) { dm = idx & 7; k3 = idx >> 3; }
  else           { dm = idx & 3; k3 = idx >> 2; }
  const int ld  = (ndir == 2) ? (dm & 1) : 0;
  const int dir = dir0 + ld;
  const int mt  = (ndir == 2) ? (dm >> 1) : dm;
  const int nt  = k3 * 8 + xcd;
  const int m0 = mt * 128, n0 = nt * 128;
  const int u0 = n0 >> 2;
  unsigned* gbar = bar + dm * 16;
  const int nb24 = 24;

  const int t0 = threadIdx.x;
  const int lane = t0 & 63;
  const int wv = t0 >> 6;            // 0..7
  const int wm = wv >> 1;            // 0..3 : 32-row band
  const int wn = wv & 1;             // 0..1 : 64-col half
  const int l15 = lane & 15, q = lane >> 4;
  const long ldoff = (ndir == 2 && ld == 1) ? (long)G4 : 0;

  const unsigned short* Bdir = whh + (long)dir * G4 * DD;
  const int srow  = lane >> 2;                               // 0..15
  const int scolA = (((lane & 3) ^ ((lane >> 3) & 3))) * 8;  // staging source slot
  const int qsw   = (q ^ ((l15 >> 1) & 3)) * 8;              // fragment read slot

  const int rb = wv * 16 + srow;                             // staged row 0..127
  // step-invariant staging bases
  const unsigned short* wB  = Bdir + (long)(n0 + rb) * DD + scolA;
  const unsigned short* hA0 = hbuf + ((long)0 * ndir + ld) * ((long)SS * DD) + (long)(m0 + rb) * DD + scolA;
  const unsigned short* hA1 = hbuf + ((long)1 * ndir + ld) * ((long)SS * DD) + (long)(m0 + rb) * DD + scolA;

  float c_reg[2][4];
  #pragma unroll
  for (int i = 0; i < 2; i++)
    #pragma unroll
    for (int j = 0; j < 4; j++)
      c_reg[i][j] = 0.f;

  for (int s = 0; s < BB; s++) {
    const int tt = dir ? (BB - 1 - s) : s;
    const unsigned short* hA = (s & 1) ? hA1 : hA0;
    unsigned short* hw = hbuf + (((long)((s + 1) & 1)) * ndir + ld) * ((long)SS * DD);

    // ---- stage super-tile 0 into buf0 (A first: L3 latency), then xg -> regs ----
    #pragma unroll
    for (int p = 0; p < 4; p++) {
      gl_lds16_c(hA + p * 32, &bufA[0][p * 4096 + wv * 512 + lane * 8]);
      gl_lds16 (wB + p * 32, &bufB[0][p * 4096 + wv * 512 + lane * 8]);
    }
    shortx4 xr0[4], xr1[4];
    {
      const unsigned short* xb = xg + ((long)tt * SS + m0) * ldxg + ldoff + n0;
      const unsigned short* xb0 = xb + (long)(wm * 32 + l15) * ldxg + wn * 64 + q * 4;
      const unsigned short* xb1 = xb0 + (long)16 * ldxg;
      #pragma unroll
      for (int j = 0; j < 4; j++) {
        xr0[j] = *(const shortx4*)(xb0 + j * 16);
        xr1[j] = *(const shortx4*)(xb1 + j * 16);
      }
    }

    floatx4 acc[2][4];
    #pragma unroll
    for (int i = 0; i < 2; i++)
      #pragma unroll
      for (int j = 0; j < 4; j++)
        acc[i][j] = (floatx4){0.f, 0.f, 0.f, 0.f};

    // ---- 6 super-tiles, double-buffered, counted vmcnt ----
    #pragma unroll
    for (int j6 = 0; j6 < 6; j6++) {
      if (j6 < 5) {                      // stage ST j6+1 into the other buffer
        const int b = (j6 + 1) & 1;
        const long kb = (long)(j6 + 1) * 128;
        #pragma unroll
        for (int p = 0; p < 4; p++) {
          gl_lds16_c(hA + kb + p * 32, &bufA[b][p * 4096 + wv * 512 + lane * 8]);
          gl_lds16 (wB + kb + p * 32, &bufB[b][p * 4096 + wv * 512 + lane * 8]);
        }
      }
      if (j6 == 0)      VMCNT(16);       // ST0 done; xg(8)+ST1(8) in flight
      else if (j6 < 5)  VMCNT(8);        // ST j6 done; ST j6+1 in flight
      else              VMCNT(0);        // ST5 done
      __builtin_amdgcn_s_barrier();      // all waves: tile landed, prev buffer free
      const int b = j6 & 1;
      __builtin_amdgcn_s_setprio(1);
      #pragma unroll
      for (int ks = 0; ks < 4; ks++) {
        const unsigned short* pA = &bufA[b][ks * 4096];
        const unsigned short* pB = &bufB[b][ks * 4096];
        short8 af[2], bfr[4];
        #pragma unroll
        for (int i = 0; i < 2; i++)
          af[i] = *(const short8*)(pA + (wm * 32 + i * 16 + l15) * 32 + qsw);
        #pragma unroll
        for (int j = 0; j < 4; j++)
          bfr[j] = *(const short8*)(pB + (wn * 64 + j * 16 + l15) * 32 + qsw);
        // TRANSPOSED: each lane's 4 acc regs = gates i,f,g,o of one unit
        #pragma unroll
        for (int i = 0; i < 2; i++)
          #pragma unroll
          for (int j = 0; j < 4; j++)
            acc[i][j] = __builtin_amdgcn_mfma_f32_16x16x32_bf16(bfr[j], af[i], acc[i][j], 0, 0, 0);
      }
      __builtin_amdgcn_s_setprio(0);
      if (j6 < 5) __builtin_amdgcn_s_barrier();  // reads of buf[b] done before overwrite
    }

    // ---- zero-shuffle gate epilogue (xg from registers) ----
    #pragma unroll
    for (int i = 0; i < 2; i++) {
      const int mrow = wm * 32 + i * 16 + l15;
      #pragma unroll
      for (int j = 0; j < 4; j++) {
        const int nb = wn * 64 + j * 16 + q * 4;
        shortx4 xv = i ? xr1[j] : xr0[j];
        float gi = acc[i][j][0] + bf2f((unsigned short)xv[0]);
        float gf = acc[i][j][1] + bf2f((unsigned short)xv[1]);
        float gg = acc[i][j][2] + bf2f((unsigned short)xv[2]);
        float go = acc[i][j][3] + bf2f((unsigned short)xv[3]);
        float c = sigf(gf) * c_reg[i][j] + sigf(gi) * tanhfast(gg);
        float h = sigf(go) * tanhfast(c);
        c_reg[i][j] = c;
        hout[mrow * 40 + (nb >> 2)] = f2bf(h);
      }
    }
    __syncthreads();
    // coalesced output: 4 threads/row, 8 shorts (16B) each
    {
      const int row = t0 >> 2;
      const int qq = t0 & 3;
      short8 v0 = *(const short8*)(hout + row * 40 + qq * 8);
      unsigned short* hwp = hw + (long)(m0 + row) * DD + u0 + qq * 8;
      unsigned short* op  = outc + ((long)tt * SS + m0 + row) * IN2 + dir * DD + u0 + qq * 8;
      store16_sc1(hwp, v0);
      *(short8*)op = v0;
    }
    if (s < BB - 1) {
      VMCNT(0);                             // only the 2 h-stores outstanding here
      __builtin_amdgcn_s_barrier();         // all waves' stores drained
      if (threadIdx.x == 0) {
        unsigned g = __hip_atomic_load(gbar + 1, __ATOMIC_RELAXED, __HIP_MEMORY_SCOPE_AGENT);
        unsigned a = __hip_atomic_fetch_add(gbar, 1u, __ATOMIC_RELAXED, __HIP_MEMORY_SCOPE_AGENT);
        if (a == (unsigned)(nb24 - 1)) {
          __hip_atomic_store(gbar, 0u, __ATOMIC_RELAXED, __HIP_MEMORY_SCOPE_AGENT);
          __hip_atomic_store(gbar + 1, g + 1u, __ATOMIC_RELEASE, __HIP_MEMORY_SCOPE_AGENT);
        } else {
          unsigned curv;
          do {
            __builtin_amdgcn_s_sleep(2);
            curv = __hip_atomic_load(gbar + 1, __ATOMIC_RELAXED, __HIP_MEMORY_SCOPE_AGENT);
          } while (curv == g);
        }
      }
      __builtin_amdgcn_s_barrier();
    }
  }
}

// ---------------- final linear [16384,1536](bf16) x [9,1536]^T ----------------
__global__ void final_linear(const unsigned short* __restrict__ xin, const float* __restrict__ w,
                             const float* __restrict__ b, float* __restrict__ out)
{
  __shared__ float red[NCLS * 256];
  int row = blockIdx.x;
  const unsigned short* x = xin + (long)row * IN2;
  float p[NCLS];
  #pragma unroll
  for (int c = 0; c < NCLS; c++) p[c] = 0.f;
  for (int k = threadIdx.x; k < IN2; k += 256) {
    float xv = bf2f(x[k]);
    #pragma unroll
    for (int c = 0; c < NCLS; c++) p[c] += xv * w[c * IN2 + k];
  }
  #pragma unroll
  for (int c = 0; c < NCLS; c++) red[c * 256 + threadIdx.x] = p[c];
  __syncthreads();
  for (int s = 128; s > 0; s >>= 1) {
    if (threadIdx.x < s) {
      #pragma unroll
      for (int c = 0; c < NCLS; c++)
        red[c * 256 + threadIdx.x] += red[c * 256 + threadIdx.x + s];
    }
    __syncthreads();
  }
  if (threadIdx.x < NCLS)
    out[(long)row * NCLS + threadIdx.x] = red[threadIdx.x * 256] + b[threadIdx.x];
}

extern "C" void kernel_launch(void* const* d_in, const int* in_sizes, int n_in,
                              void* d_out, int out_size, void* d_ws, size_t ws_size,
                              hipStream_t stream)
{
  const int*   batch  = (const int*)d_in[0];
  const float* hidden = (const float*)d_in[1];
  const float* w_ih_f = (const float*)d_in[2];
  const float* w_hh_f = (const float*)d_in[3];
  const float* b_ih_f = (const float*)d_in[4];
  const float* b_hh_f = (const float*)d_in[5];
  const float* w_ih_b = (const float*)d_in[6];
  const float* w_hh_b = (const float*)d_in[7];
  const float* b_ih_b = (const float*)d_in[8];
  const float* b_hh_b = (const float*)d_in[9];
  const float* lin_w  = (const float*)d_in[10];
  const float* lin_b  = (const float*)d_in[11];
  float* out = (float*)d_out;

  char* ws = (char*)d_ws;
  size_t off = 0;
  auto alloc = [&](size_t bytes) -> char* {
    char* p = ws + off;
    off += (bytes + 255) & ~(size_t)255;
    return p;
  };

  const size_t SZ_XG_A = (size_t)ROWS * NB2 * 2;      // 201.3 MB
  const size_t SZ_XG_B = (size_t)ROWS * G4  * 2;      // 100.7 MB
  const size_t SZ_XBF  = (size_t)ROWS * IN2 * 2;      //  50.3 MB
  const size_t SZ_W    = (size_t)G4 * IN2 * 2;        //   9.4 MB
  const size_t SZ_BIAS = (size_t)NB2 * 4;
  const size_t SZ_HBUF = (size_t)2 * 2 * SS * DD * 2; //   3.1 MB
  const size_t SZ_BAR  = 512;
  const size_t SZ_SUMS = (size_t)VOCAB * DD * 4 + (size_t)VOCAB * 4;

  const size_t NEED_C = SZ_XG_A + SZ_XBF + SZ_W + SZ_BIAS + SZ_HBUF + SZ_BAR + 8 * 256;
  const bool combined = ws_size >= NEED_C;

  const long nWIH = (long)G4 * IN2;
  const long nWHH = (long)G4 * DD;

  if (combined) {
    unsigned short* xg   = (unsigned short*)alloc(SZ_XG_A);
    unsigned short* xbf  = (unsigned short*)alloc(SZ_XBF);   // x input, later reused as outc
    unsigned short* wbuf = (unsigned short*)alloc(SZ_W);     // wih_f -> wih_b -> whh(both)
    float*          bias = (float*)alloc(SZ_BIAS);
    unsigned short* hbuf = (unsigned short*)alloc(SZ_HBUF);
    unsigned*       bar  = (unsigned*)alloc(SZ_BAR);
    float* sums   = (float*)xg;                              // overlay, consumed pre-xg-GEMM
    float* counts = sums + (size_t)VOCAB * DD;

    hipMemsetAsync(sums, 0, SZ_SUMS, stream);
    hipMemsetAsync(bar, 0, SZ_BAR, stream);
    seg_scatter<<<ROWS, 256, 0, stream>>>(batch, hidden, sums, counts);
    build_x<<<ROWS, 256, 0, stream>>>(batch, hidden, sums, counts, xbf);
    conv_bias_perm<<<(NB2 + 255) / 256, 256, 0, stream>>>(b_ih_f, b_hh_f, b_ih_b, b_hh_b, bias);

    for (int dir = 0; dir < 2; dir++) {
      conv_w_perm<<<(unsigned)((nWIH + 255) / 256), 256, 0, stream>>>(dir ? w_ih_b : w_ih_f, wbuf, IN2);
      dim3 grid(G4 / 128, ROWS / 128, 1);
      gemm_bt<<<grid, 256, 0, stream>>>(xbf, IN2, wbuf, IN2,
                                        xg + (size_t)dir * G4, NB2,
                                        bias + (size_t)dir * G4, IN2);
    }
    conv_w_perm<<<(unsigned)((nWHH + 255) / 256), 256, 0, stream>>>(w_hh_f, wbuf, DD);
    conv_w_perm<<<(unsigned)((nWHH + 255) / 256), 256, 0, stream>>>(w_hh_b, wbuf + (size_t)G4 * DD, DD);

    hipMemsetAsync(hbuf, 0, SZ_HBUF, stream);
    lstm_persist<<<192, 512, 0, stream>>>(xg, NB2, wbuf, hbuf, xbf, bar, 0, 2);
    final_linear<<<ROWS, 256, 0, stream>>>(xbf, lin_w, lin_b, out);
  } else {
    // direction-sequential (~223 MB, proven to fit)
    unsigned short* xg   = (unsigned short*)alloc(SZ_XG_B);
    unsigned short* xbf  = (unsigned short*)alloc(SZ_XBF);
    unsigned short* outc = (unsigned short*)alloc(SZ_XBF);
    unsigned short* wih  = (unsigned short*)alloc(SZ_W);
    unsigned short* whh  = (unsigned short*)alloc(SZ_W);
    float*          bias = (float*)alloc(SZ_BIAS);
    unsigned short* hbuf = (unsigned short*)alloc(SZ_HBUF);
    unsigned*       bar  = (unsigned*)alloc(SZ_BAR);
    float* sums   = (float*)xg;
    float* counts = sums + (size_t)VOCAB * DD;

    hipMemsetAsync(sums, 0, SZ_SUMS, stream);
    hipMemsetAsync(bar, 0, SZ_BAR, stream);
    seg_scatter<<<ROWS, 256, 0, stream>>>(batch, hidden, sums, counts);
    build_x<<<ROWS, 256, 0, stream>>>(batch, hidden, sums, counts, xbf);
    conv_bias_perm<<<(NB2 + 255) / 256, 256, 0, stream>>>(b_ih_f, b_hh_f, b_ih_b, b_hh_b, bias);
    conv_w_perm<<<(unsigned)((nWHH + 255) / 256), 256, 0, stream>>>(w_hh_f, whh, DD);
    conv_w_perm<<<(unsigned)((nWHH + 255) / 256), 256, 0, stream>>>(w_hh_b, whh + (size_t)G4 * DD, DD);

    for (int dir = 0; dir < 2; dir++) {
      conv_w_perm<<<(unsigned)((nWIH + 255) / 256), 256, 0, stream>>>(dir ? w_ih_b : w_ih_f, wih, IN2);
      {
        dim3 grid(G4 / 128, ROWS / 128, 1);
        gemm_bt<<<grid, 256, 0, stream>>>(xbf, IN2, wih, IN2, xg, G4,
                                          bias + (size_t)dir * G4, IN2);
      }
      hipMemsetAsync(hbuf, 0, SZ_HBUF, stream);
      lstm_persist<<<96, 512, 0, stream>>>(xg, G4, whh, hbuf, outc, bar, dir, 1);
    }
    final_linear<<<ROWS, 256, 0, stream>>>(outc, lin_w, lin_b, out);
  }
}

// Round 6
// 1168.875 us; speedup vs baseline: 1.0564x; 1.0564x over previous
//
#include <hip/hip_runtime.h>

#define VOCAB 28996
#define BB 32
#define SS 512
#define DD 768
#define NCLS 9
#define ROWS (BB*SS)     // 16384
#define IN2 (2*DD)       // 1536
#define G4 (4*DD)        // 3072
#define NB2 (2*G4)       // 6144

typedef __attribute__((ext_vector_type(8))) short short8;
typedef __attribute__((ext_vector_type(4))) short shortx4;
typedef __attribute__((ext_vector_type(4))) float floatx4;
typedef unsigned long long ull;

__device__ __forceinline__ float bf2f(unsigned short u){
  union { unsigned int i; float f; } v; v.i = ((unsigned int)u) << 16; return v.f;
}
__device__ __forceinline__ unsigned short f2bf(float f){
  union { float f; unsigned int i; } v; v.f = f;
  unsigned int r = v.i + 0x7FFFu + ((v.i >> 16) & 1u);
  return (unsigned short)(r >> 16);
}
__device__ __forceinline__ float sigf(float x){ return 1.0f / (1.0f + __expf(-x)); }
__device__ __forceinline__ float tanhfast(float x){
  float y = fminf(fmaxf(x, -15.f), 15.f);
  float e = __expf(2.f * y);
  return 1.f - 2.f / (e + 1.f);
}

__device__ __forceinline__ void gl_lds16(const unsigned short* g, unsigned short* l){
  __builtin_amdgcn_global_load_lds((__attribute__((address_space(1))) void*)(g),
                                   (__attribute__((address_space(3))) void*)(l), 16, 0, 0);
}
// coherent variant: sc0|sc1 -> bypass L1+L2, read memory-side L3 (h path only)
__device__ __forceinline__ void gl_lds16_c(const unsigned short* g, unsigned short* l){
  __builtin_amdgcn_global_load_lds((__attribute__((address_space(1))) void*)(g),
                                   (__attribute__((address_space(3))) void*)(l), 16, 0, 17);
}
// write-through store to the coherence point (L3) so sc1 readers on other XCDs see it
__device__ __forceinline__ void store16_sc1(unsigned short* p, short8 v){
  asm volatile("global_store_dwordx4 %0, %1, off sc0 sc1" :: "v"(p), "v"(v) : "memory");
}

#define VMCNT(n) do { asm volatile("s_waitcnt vmcnt(" #n ")" ::: "memory"); \
                      __builtin_amdgcn_sched_barrier(0); } while (0)

// ---------------- segment mean ----------------
__global__ void seg_scatter(const int* __restrict__ ids, const float* __restrict__ hidden,
                            float* __restrict__ sums, float* __restrict__ counts)
{
  int r = blockIdx.x;
  int id = ids[r];
  const float* h = hidden + (long)r * DD;
  float* s = sums + (long)id * DD;
  for (int d = threadIdx.x; d < DD; d += 256)
    atomicAdd(&s[d], h[d]);
  if (threadIdx.x == 0) atomicAdd(&counts[id], 1.0f);
}

__global__ void build_x(const int* __restrict__ ids, const float* __restrict__ hidden,
                        const float* __restrict__ sums, const float* __restrict__ counts,
                        unsigned short* __restrict__ x)
{
  int r = blockIdx.x;
  int id = ids[r];
  float inv = 1.0f / fmaxf(counts[id], 1.0f);
  const float* h = hidden + (long)r * DD;
  const float* s = sums + (long)id * DD;
  unsigned short* xr = x + (long)r * IN2;
  for (int d = threadIdx.x; d < DD; d += 256) {
    xr[d]      = f2bf(h[d]);
    xr[DD + d] = f2bf(s[d] * inv);
  }
}

// -------- weight conversion with gate-interleave permutation: row' = u*4+g <- row g*768+u --------
__global__ void conv_w_perm(const float* __restrict__ w, unsigned short* __restrict__ o, int K)
{
  long i = (long)blockIdx.x * 256 + threadIdx.x;
  if (i >= (long)G4 * K) return;
  int row = (int)(i / K); int k = (int)(i - (long)row * K);
  int u = row >> 2, g = row & 3;
  o[i] = f2bf(w[((long)(g * DD + u)) * K + k]);
}

__global__ void conv_bias_perm(const float* __restrict__ bif, const float* __restrict__ bhf,
                               const float* __restrict__ bib, const float* __restrict__ bhb,
                               float* __restrict__ o)
{
  int n = blockIdx.x * 256 + threadIdx.x;
  if (n >= NB2) return;
  int d = n / G4, rr = n - d * G4, u = rr >> 2, g = rr & 3;
  int s = g * DD + u;
  o[n] = d ? (bib[s] + bhb[s]) : (bif[s] + bhf[s]);
}

// ---------------- 256x256-tile GEMM: C[m,n] = sum_k A[m,k]*B[n,k] + bias[n] ----------------
// 512 threads / 8 waves, wave-tile 64x128. K-tile 64, double-buffered (128 KB LDS).
// Phase-interleaved staging: the 8 global_load_lds pieces of tile kt+1 are issued 2-per-phase
// between the MFMA quadrants of tile kt; counted vmcnt(4) at the two data points per tile
// (never 0 mid-loop). Piece order (Ap0h0,Bp0h0,Ap0h1,Bp0h1 | Ap1..) matches in-order retire:
// VMCNT(4) at tile top == ks0 panels landed; VMCNT(4) mid-tile == ks1 panels landed.
// LDS invariant (proven in lstm/gemm128): LDS[r][slot s] = global k-slot (s ^ ((r>>1)&3)).
__global__ __launch_bounds__(512, 1)
void gemm_bt256(const unsigned short* __restrict__ A, int lda,
                const unsigned short* __restrict__ B, int ldb,
                unsigned short* __restrict__ C, int ldc,
                const float* __restrict__ bias, int K)
{
  __shared__ unsigned short lA[2][16384];   // [buf][panel p][half hf][128 rows][4 slots x 16B]
  __shared__ unsigned short lB[2][16384];
  const int t = threadIdx.x;
  const int lane = t & 63;
  const int wv = t >> 6;          // 0..7
  const int wm = wv >> 1;         // 0..3 : 64-row band
  const int wn = wv & 1;          // 0..1 : 128-col half
  const int l15 = lane & 15, q = lane >> 4;
  const long m0 = (long)blockIdx.x * 256;   // x = m-tile: consecutive bids share the B n-panel
  const long n0 = (long)blockIdx.y * 256;
  const int rs  = t >> 2;                               // staged row 0..127 (+hf*128)
  const int sc  = (((t & 3) ^ ((t >> 3) & 3))) * 8;     // swizzled source slot (shorts)
  const int qsw = (q ^ ((l15 >> 1) & 3)) * 8;           // fragment read slot (shorts)

  const unsigned short* gA = A + (m0 + rs) * (long)lda + sc;
  const unsigned short* gB = B + (n0 + rs) * (long)ldb + sc;
  const long a128 = (long)128 * lda;
  const long b128 = (long)128 * ldb;

  // stage piece (p,hf) of k-tile kt into buffer b: one A + one B instruction
  #define PIECE(b, kt, p, hf) do {                                               \
    const long kb_ = (long)(kt) * 64 + (p) * 32 + (hf) * 0;                      \
    gl_lds16(gA + kb_ + (hf) * a128, &lA[b][(p) * 8192 + (hf) * 4096 + t * 8]);  \
    gl_lds16(gB + kb_ + (hf) * b128, &lB[b][(p) * 8192 + (hf) * 4096 + t * 8]);  \
  } while (0)

  floatx4 acc[4][8];
  #pragma unroll
  for (int i = 0; i < 4; i++)
    #pragma unroll
    for (int j = 0; j < 8; j++)
      acc[i][j] = (floatx4){0.f, 0.f, 0.f, 0.f};

  // prologue: all 8 pieces of tile 0, ks0 panels first
  PIECE(0, 0, 0, 0); PIECE(0, 0, 0, 1);
  PIECE(0, 0, 1, 0); PIECE(0, 0, 1, 1);

  #pragma unroll 2
  for (int kt = 0; kt < 24; kt++) {
    const int cur = kt & 1;
    const int nxt = cur ^ 1;
    const unsigned short* pA = &lA[cur][0];
    const unsigned short* pB = &lB[cur][0];

    VMCNT(4);                           // ks0 panels of tile kt landed (per-wave)
    __builtin_amdgcn_s_barrier();       // ... for ALL waves

    #pragma unroll
    for (int ks = 0; ks < 2; ks++) {
      short8 bfr[8];
      #pragma unroll
      for (int ih = 0; ih < 2; ih++) {
        // issue 1 staging piece for tile kt+1 (phase-distributed)
        if (kt < 23) {
          if (ks == 0 && ih == 0) PIECE(nxt, kt + 1, 0, 0);
          if (ks == 0 && ih == 1) PIECE(nxt, kt + 1, 0, 1);
          if (ks == 1 && ih == 0) PIECE(nxt, kt + 1, 1, 0);
          if (ks == 1 && ih == 1) PIECE(nxt, kt + 1, 1, 1);
        }
        if (ih == 0) {
          #pragma unroll
          for (int j = 0; j < 8; j++)
            bfr[j] = *(const short8*)(pB + ks * 8192 + (wn * 128 + j * 16 + l15) * 32 + qsw);
        }
        short8 af[2];
        #pragma unroll
        for (int ii = 0; ii < 2; ii++)
          af[ii] = *(const short8*)(pA + ks * 8192 + (wm * 64 + (ih * 2 + ii) * 16 + l15) * 32 + qsw);
        __builtin_amdgcn_s_setprio(1);
        #pragma unroll
        for (int ii = 0; ii < 2; ii++)
          #pragma unroll
          for (int j = 0; j < 8; j++)
            acc[ih * 2 + ii][j] =
              __builtin_amdgcn_mfma_f32_16x16x32_bf16(af[ii], bfr[j], acc[ih * 2 + ii][j], 0, 0, 0);
        __builtin_amdgcn_s_setprio(0);
      }
      if (ks == 0) {                    // before ks1 reads: ks1 panels must be in LDS
        if (kt < 23) VMCNT(4); else VMCNT(0);
        __builtin_amdgcn_s_barrier();
      }
    }
    // next iteration's top VMCNT+barrier protects buf[nxt] overwrite ordering
  }
  #undef PIECE

  #pragma unroll
  for (int i = 0; i < 4; i++) {
    #pragma unroll
    for (int j = 0; j < 8; j++) {
      const long mg = m0 + wm * 64 + i * 16 + q * 4;
      const long ng = n0 + wn * 128 + j * 16 + l15;
      const float bb = bias[ng];
      #pragma unroll
      for (int r = 0; r < 4; r++)
        C[(mg + r) * (long)ldc + ng] = f2bf(acc[i][j][r] + bb);
    }
  }
}

// ---------------- persistent bidirectional LSTM recurrence (frozen from R5) ----------------
__global__ __launch_bounds__(512, 1)
void lstm_persist(const unsigned short* __restrict__ xg, int ldxg,
                  const unsigned short* __restrict__ whh,   // [2][3072][768] permuted
                  unsigned short* __restrict__ hbuf,        // [2][ndir][512][768]
                  unsigned short* __restrict__ outc,        // [16384][1536]
                  unsigned* bar,                            // 8 groups x 16 u32
                  int dir0, int ndir)
{
  __shared__ unsigned short bufA[2][16384];   // dbuf x 4 panels [128][32], swizzled
  __shared__ unsigned short bufB[2][16384];
  __shared__ unsigned short hout[128 * 40];   // h staging, pad 40

  const int bid = blockIdx.x;
  const int xcd = bid & 7;
  const int idx = bid >> 3;
  int dm, k3;
  if (ndir == 2) { dm = idx & 7; k3 = idx >> 3; }
  else           { dm = idx & 3; k3 = idx >> 2; }
  const int ld  = (ndir == 2) ? (dm & 1) : 0;
  const int dir = dir0 + ld;
  const int mt  = (ndir == 2) ? (dm >> 1) : dm;
  const int nt  = k3 * 8 + xcd;
  const int m0 = mt * 128, n0 = nt * 128;
  const int u0 = n0 >> 2;
  unsigned* gbar = bar + dm * 16;
  const int nb24 = 24;

  const int t0 = threadIdx.x;
  const int lane = t0 & 63;
  const int wv = t0 >> 6;            // 0..7
  const int wm = wv >> 1;            // 0..3 : 32-row band
  const int wn = wv & 1;             // 0..1 : 64-col half
  const int l15 = lane & 15, q = lane >> 4;
  const long ldoff = (ndir == 2 && ld == 1) ? (long)G4 : 0;

  const unsigned short* Bdir = whh + (long)dir * G4 * DD;
  const int srow  = lane >> 2;                               // 0..15
  const int scolA = (((lane & 3) ^ ((lane >> 3) & 3))) * 8;  // staging source slot
  const int qsw   = (q ^ ((l15 >> 1) & 3)) * 8;              // fragment read slot

  const int rb = wv * 16 + srow;                             // staged row 0..127
  const unsigned short* wB  = Bdir + (long)(n0 + rb) * DD + scolA;
  const unsigned short* hA0 = hbuf + ((long)0 * ndir + ld) * ((long)SS * DD) + (long)(m0 + rb) * DD + scolA;
  const unsigned short* hA1 = hbuf + ((long)1 * ndir + ld) * ((long)SS * DD) + (long)(m0 + rb) * DD + scolA;

  float c_reg[2][4];
  #pragma unroll
  for (int i = 0; i < 2; i++)
    #pragma unroll
    for (int j = 0; j < 4; j++)
      c_reg[i][j] = 0.f;

  for (int s = 0; s < BB; s++) {
    const int tt = dir ? (BB - 1 - s) : s;
    const unsigned short* hA = (s & 1) ? hA1 : hA0;
    unsigned short* hw = hbuf + (((long)((s + 1) & 1)) * ndir + ld) * ((long)SS * DD);

    #pragma unroll
    for (int p = 0; p < 4; p++) {
      gl_lds16_c(hA + p * 32, &bufA[0][p * 4096 + wv * 512 + lane * 8]);
      gl_lds16 (wB + p * 32, &bufB[0][p * 4096 + wv * 512 + lane * 8]);
    }
    shortx4 xr0[4], xr1[4];
    {
      const unsigned short* xb = xg + ((long)tt * SS + m0) * ldxg + ldoff + n0;
      const unsigned short* xb0 = xb + (long)(wm * 32 + l15) * ldxg + wn * 64 + q * 4;
      const unsigned short* xb1 = xb0 + (long)16 * ldxg;
      #pragma unroll
      for (int j = 0; j < 4; j++) {
        xr0[j] = *(const shortx4*)(xb0 + j * 16);
        xr1[j] = *(const shortx4*)(xb1 + j * 16);
      }
    }

    floatx4 acc[2][4];
    #pragma unroll
    for (int i = 0; i < 2; i++)
      #pragma unroll
      for (int j = 0; j < 4; j++)
        acc[i][j] = (floatx4){0.f, 0.f, 0.f, 0.f};

    #pragma unroll
    for (int j6 = 0; j6 < 6; j6++) {
      if (j6 < 5) {
        const int b = (j6 + 1) & 1;
        const long kb = (long)(j6 + 1) * 128;
        #pragma unroll
        for (int p = 0; p < 4; p++) {
          gl_lds16_c(hA + kb + p * 32, &bufA[b][p * 4096 + wv * 512 + lane * 8]);
          gl_lds16 (wB + kb + p * 32, &bufB[b][p * 4096 + wv * 512 + lane * 8]);
        }
      }
      if (j6 == 0)      VMCNT(16);
      else if (j6 < 5)  VMCNT(8);
      else              VMCNT(0);
      __builtin_amdgcn_s_barrier();
      const int b = j6 & 1;
      __builtin_amdgcn_s_setprio(1);
      #pragma unroll
      for (int ks = 0; ks < 4; ks++) {
        const unsigned short* pA = &bufA[b][ks * 4096];
        const unsigned short* pB = &bufB[b][ks * 4096];
        short8 af[2], bfr[4];
        #pragma unroll
        for (int i = 0; i < 2; i++)
          af[i] = *(const short8*)(pA + (wm * 32 + i * 16 + l15) * 32 + qsw);
        #pragma unroll
        for (int j = 0; j < 4; j++)
          bfr[j] = *(const short8*)(pB + (wn * 64 + j * 16 + l15) * 32 + qsw);
        #pragma unroll
        for (int i = 0; i < 2; i++)
          #pragma unroll
          for (int j = 0; j < 4; j++)
            acc[i][j] = __builtin_amdgcn_mfma_f32_16x16x32_bf16(bfr[j], af[i], acc[i][j], 0, 0, 0);
      }
      __builtin_amdgcn_s_setprio(0);
      if (j6 < 5) __builtin_amdgcn_s_barrier();
    }

    #pragma unroll
    for (int i = 0; i < 2; i++) {
      const int mrow = wm * 32 + i * 16 + l15;
      #pragma unroll
      for (int j = 0; j < 4; j++) {
        const int nb = wn * 64 + j * 16 + q * 4;
        shortx4 xv = i ? xr1[j] : xr0[j];
        float gi = acc[i][j][0] + bf2f((unsigned short)xv[0]);
        float gf = acc[i][j][1] + bf2f((unsigned short)xv[1]);
        float gg = acc[i][j][2] + bf2f((unsigned short)xv[2]);
        float go = acc[i][j][3] + bf2f((unsigned short)xv[3]);
        float c = sigf(gf) * c_reg[i][j] + sigf(gi) * tanhfast(gg);
        float h = sigf(go) * tanhfast(c);
        c_reg[i][j] = c;
        hout[mrow * 40 + (nb >> 2)] = f2bf(h);
      }
    }
    __syncthreads();
    {
      const int row = t0 >> 2;
      const int qq = t0 & 3;
      short8 v0 = *(const short8*)(hout + row * 40 + qq * 8);
      unsigned short* hwp = hw + (long)(m0 + row) * DD + u0 + qq * 8;
      unsigned short* op  = outc + ((long)tt * SS + m0 + row) * IN2 + dir * DD + u0 + qq * 8;
      store16_sc1(hwp, v0);
      *(short8*)op = v0;
    }
    if (s < BB - 1) {
      VMCNT(0);
      __builtin_amdgcn_s_barrier();
      if (threadIdx.x == 0) {
        unsigned g = __hip_atomic_load(gbar + 1, __ATOMIC_RELAXED, __HIP_MEMORY_SCOPE_AGENT);
        unsigned a = __hip_atomic_fetch_add(gbar, 1u, __ATOMIC_RELAXED, __HIP_MEMORY_SCOPE_AGENT);
        if (a == (unsigned)(nb24 - 1)) {
          __hip_atomic_store(gbar, 0u, __ATOMIC_RELAXED, __HIP_MEMORY_SCOPE_AGENT);
          __hip_atomic_store(gbar + 1, g + 1u, __ATOMIC_RELEASE, __HIP_MEMORY_SCOPE_AGENT);
        } else {
          unsigned curv;
          do {
            __builtin_amdgcn_s_sleep(2);
            curv = __hip_atomic_load(gbar + 1, __ATOMIC_RELAXED, __HIP_MEMORY_SCOPE_AGENT);
          } while (curv == g);
        }
      }
      __builtin_amdgcn_s_barrier();
    }
  }
}

// ---------------- final linear [16384,1536](bf16) x [9,1536]^T ----------------
__global__ void final_linear(const unsigned short* __restrict__ xin, const float* __restrict__ w,
                             const float* __restrict__ b, float* __restrict__ out)
{
  __shared__ float red[NCLS * 256];
  int row = blockIdx.x;
  const unsigned short* x = xin + (long)row * IN2;
  float p[NCLS];
  #pragma unroll
  for (int c = 0; c < NCLS; c++) p[c] = 0.f;
  for (int k = threadIdx.x; k < IN2; k += 256) {
    float xv = bf2f(x[k]);
    #pragma unroll
    for (int c = 0; c < NCLS; c++) p[c] += xv * w[c * IN2 + k];
  }
  #pragma unroll
  for (int c = 0; c < NCLS; c++) red[c * 256 + threadIdx.x] = p[c];
  __syncthreads();
  for (int s = 128; s > 0; s >>= 1) {
    if (threadIdx.x < s) {
      #pragma unroll
      for (int c = 0; c < NCLS; c++)
        red[c * 256 + threadIdx.x] += red[c * 256 + threadIdx.x + s];
    }
    __syncthreads();
  }
  if (threadIdx.x < NCLS)
    out[(long)row * NCLS + threadIdx.x] = red[threadIdx.x * 256] + b[threadIdx.x];
}

extern "C" void kernel_launch(void* const* d_in, const int* in_sizes, int n_in,
                              void* d_out, int out_size, void* d_ws, size_t ws_size,
                              hipStream_t stream)
{
  const int*   batch  = (const int*)d_in[0];
  const float* hidden = (const float*)d_in[1];
  const float* w_ih_f = (const float*)d_in[2];
  const float* w_hh_f = (const float*)d_in[3];
  const float* b_ih_f = (const float*)d_in[4];
  const float* b_hh_f = (const float*)d_in[5];
  const float* w_ih_b = (const float*)d_in[6];
  const float* w_hh_b = (const float*)d_in[7];
  const float* b_ih_b = (const float*)d_in[8];
  const float* b_hh_b = (const float*)d_in[9];
  const float* lin_w  = (const float*)d_in[10];
  const float* lin_b  = (const float*)d_in[11];
  float* out = (float*)d_out;

  char* ws = (char*)d_ws;
  size_t off = 0;
  auto alloc = [&](size_t bytes) -> char* {
    char* p = ws + off;
    off += (bytes + 255) & ~(size_t)255;
    return p;
  };

  const size_t SZ_XG_A = (size_t)ROWS * NB2 * 2;      // 201.3 MB
  const size_t SZ_XG_B = (size_t)ROWS * G4  * 2;      // 100.7 MB
  const size_t SZ_XBF  = (size_t)ROWS * IN2 * 2;      //  50.3 MB
  const size_t SZ_W    = (size_t)G4 * IN2 * 2;        //   9.4 MB
  const size_t SZ_BIAS = (size_t)NB2 * 4;
  const size_t SZ_HBUF = (size_t)2 * 2 * SS * DD * 2; //   3.1 MB
  const size_t SZ_BAR  = 512;
  const size_t SZ_SUMS = (size_t)VOCAB * DD * 4 + (size_t)VOCAB * 4;

  const size_t NEED_C = SZ_XG_A + SZ_XBF + SZ_W + SZ_BIAS + SZ_HBUF + SZ_BAR + 8 * 256;
  const bool combined = ws_size >= NEED_C;

  const long nWIH = (long)G4 * IN2;
  const long nWHH = (long)G4 * DD;

  if (combined) {
    unsigned short* xg   = (unsigned short*)alloc(SZ_XG_A);
    unsigned short* xbf  = (unsigned short*)alloc(SZ_XBF);   // x input, later reused as outc
    unsigned short* wbuf = (unsigned short*)alloc(SZ_W);     // wih_f -> wih_b -> whh(both)
    float*          bias = (float*)alloc(SZ_BIAS);
    unsigned short* hbuf = (unsigned short*)alloc(SZ_HBUF);
    unsigned*       bar  = (unsigned*)alloc(SZ_BAR);
    float* sums   = (float*)xg;                              // overlay, consumed pre-xg-GEMM
    float* counts = sums + (size_t)VOCAB * DD;

    hipMemsetAsync(sums, 0, SZ_SUMS, stream);
    hipMemsetAsync(bar, 0, SZ_BAR, stream);
    seg_scatter<<<ROWS, 256, 0, stream>>>(batch, hidden, sums, counts);
    build_x<<<ROWS, 256, 0, stream>>>(batch, hidden, sums, counts, xbf);
    conv_bias_perm<<<(NB2 + 255) / 256, 256, 0, stream>>>(b_ih_f, b_hh_f, b_ih_b, b_hh_b, bias);

    for (int dir = 0; dir < 2; dir++) {
      conv_w_perm<<<(unsigned)((nWIH + 255) / 256), 256, 0, stream>>>(dir ? w_ih_b : w_ih_f, wbuf, IN2);
      dim3 grid(ROWS / 256, G4 / 256, 1);
      gemm_bt256<<<grid, 512, 0, stream>>>(xbf, IN2, wbuf, IN2,
                                           xg + (size_t)dir * G4, NB2,
                                           bias + (size_t)dir * G4, IN2);
    }
    conv_w_perm<<<(unsigned)((nWHH + 255) / 256), 256, 0, stream>>>(w_hh_f, wbuf, DD);
    conv_w_perm<<<(unsigned)((nWHH + 255) / 256), 256, 0, stream>>>(w_hh_b, wbuf + (size_t)G4 * DD, DD);

    hipMemsetAsync(hbuf, 0, SZ_HBUF, stream);
    lstm_persist<<<192, 512, 0, stream>>>(xg, NB2, wbuf, hbuf, xbf, bar, 0, 2);
    final_linear<<<ROWS, 256, 0, stream>>>(xbf, lin_w, lin_b, out);
  } else {
    // direction-sequential (~223 MB, proven to fit)
    unsigned short* xg   = (unsigned short*)alloc(SZ_XG_B);
    unsigned short* xbf  = (unsigned short*)alloc(SZ_XBF);
    unsigned short* outc = (unsigned short*)alloc(SZ_XBF);
    unsigned short* wih  = (unsigned short*)alloc(SZ_W);
    unsigned short* whh  = (unsigned short*)alloc(SZ_W);
    float*          bias = (float*)alloc(SZ_BIAS);
    unsigned short* hbuf = (unsigned short*)alloc(SZ_HBUF);
    unsigned*       bar  = (unsigned*)alloc(SZ_BAR);
    float* sums   = (float*)xg;
    float* counts = sums + (size_t)VOCAB * DD;

    hipMemsetAsync(sums, 0, SZ_SUMS, stream);
    hipMemsetAsync(bar, 0, SZ_BAR, stream);
    seg_scatter<<<ROWS, 256, 0, stream>>>(batch, hidden, sums, counts);
    build_x<<<ROWS, 256, 0, stream>>>(batch, hidden, sums, counts, xbf);
    conv_bias_perm<<<(NB2 + 255) / 256, 256, 0, stream>>>(b_ih_f, b_hh_f, b_ih_b, b_hh_b, bias);
    conv_w_perm<<<(unsigned)((nWHH + 255) / 256), 256, 0, stream>>>(w_hh_f, whh, DD);
    conv_w_perm<<<(unsigned)((nWHH + 255) / 256), 256, 0, stream>>>(w_hh_b, whh + (size_t)G4 * DD, DD);

    for (int dir = 0; dir < 2; dir++) {
      conv_w_perm<<<(unsigned)((nWIH + 255) / 256), 256, 0, stream>>>(dir ? w_ih_b : w_ih_f, wih, IN2);
      {
        dim3 grid(ROWS / 256, G4 / 256, 1);
        gemm_bt256<<<grid, 512, 0, stream>>>(xbf, IN2, wih, IN2, xg, G4,
                                             bias + (size_t)dir * G4, IN2);
      }
      hipMemsetAsync(hbuf, 0, SZ_HBUF, stream);
      lstm_persist<<<96, 512, 0, stream>>>(xg, G4, whh, hbuf, outc, bar, dir, 1);
    }
    final_linear<<<ROWS, 256, 0, stream>>>(outc, lin_w, lin_b, out);
  }
}

// Round 7
// 1135.814 us; speedup vs baseline: 1.0872x; 1.0291x over previous
//
#include <hip/hip_runtime.h>

#define VOCAB 28996
#define BB 32
#define SS 512
#define DD 768
#define NCLS 9
#define ROWS (BB*SS)     // 16384
#define IN2 (2*DD)       // 1536
#define G4 (4*DD)        // 3072
#define NB2 (2*G4)       // 6144

typedef __attribute__((ext_vector_type(8))) short short8;
typedef __attribute__((ext_vector_type(4))) short shortx4;
typedef __attribute__((ext_vector_type(4))) float floatx4;
typedef unsigned long long ull;

__device__ __forceinline__ float bf2f(unsigned short u){
  union { unsigned int i; float f; } v; v.i = ((unsigned int)u) << 16; return v.f;
}
__device__ __forceinline__ unsigned short f2bf(float f){
  union { float f; unsigned int i; } v; v.f = f;
  unsigned int r = v.i + 0x7FFFu + ((v.i >> 16) & 1u);
  return (unsigned short)(r >> 16);
}
__device__ __forceinline__ float sigf(float x){ return 1.0f / (1.0f + __expf(-x)); }
__device__ __forceinline__ float tanhfast(float x){
  float y = fminf(fmaxf(x, -15.f), 15.f);
  float e = __expf(2.f * y);
  return 1.f - 2.f / (e + 1.f);
}

__device__ __forceinline__ void gl_lds16(const unsigned short* g, unsigned short* l){
  __builtin_amdgcn_global_load_lds((__attribute__((address_space(1))) void*)(g),
                                   (__attribute__((address_space(3))) void*)(l), 16, 0, 0);
}
// h-path load, parameterized coherence:
// LOCAL=1: sc0 only -> bypass L1, read the block's own XCD L2 (producers same-XCD)
// LOCAL=0: sc0|sc1  -> bypass L1+L2, read memory-side L3 (producers cross-XCD)
template<int LOCAL>
__device__ __forceinline__ void gl_lds16_h(const unsigned short* g, unsigned short* l){
  __builtin_amdgcn_global_load_lds((__attribute__((address_space(1))) void*)(g),
                                   (__attribute__((address_space(3))) void*)(l), 16, 0,
                                   LOCAL ? 1 : 17);
}
// write-through store to the coherence point (L3) so sc1 readers on other XCDs see it
__device__ __forceinline__ void store16_sc1(unsigned short* p, short8 v){
  asm volatile("global_store_dwordx4 %0, %1, off sc0 sc1" :: "v"(p), "v"(v) : "memory");
}

#define VMCNT(n) do { asm volatile("s_waitcnt vmcnt(" #n ")" ::: "memory"); \
                      __builtin_amdgcn_sched_barrier(0); } while (0)

// ---------------- segment mean ----------------
__global__ void seg_scatter(const int* __restrict__ ids, const float* __restrict__ hidden,
                            float* __restrict__ sums, float* __restrict__ counts)
{
  int r = blockIdx.x;
  int id = ids[r];
  const float* h = hidden + (long)r * DD;
  float* s = sums + (long)id * DD;
  for (int d = threadIdx.x; d < DD; d += 256)
    atomicAdd(&s[d], h[d]);
  if (threadIdx.x == 0) atomicAdd(&counts[id], 1.0f);
}

__global__ void build_x(const int* __restrict__ ids, const float* __restrict__ hidden,
                        const float* __restrict__ sums, const float* __restrict__ counts,
                        unsigned short* __restrict__ x)
{
  int r = blockIdx.x;
  int id = ids[r];
  float inv = 1.0f / fmaxf(counts[id], 1.0f);
  const float* h = hidden + (long)r * DD;
  const float* s = sums + (long)id * DD;
  unsigned short* xr = x + (long)r * IN2;
  for (int d = threadIdx.x; d < DD; d += 256) {
    xr[d]      = f2bf(h[d]);
    xr[DD + d] = f2bf(s[d] * inv);
  }
}

// -------- weight conversion with gate-interleave permutation: row' = u*4+g <- row g*768+u --------
__global__ void conv_w_perm(const float* __restrict__ w, unsigned short* __restrict__ o, int K)
{
  long i = (long)blockIdx.x * 256 + threadIdx.x;
  if (i >= (long)G4 * K) return;
  int row = (int)(i / K); int k = (int)(i - (long)row * K);
  int u = row >> 2, g = row & 3;
  o[i] = f2bf(w[((long)(g * DD + u)) * K + k]);
}

__global__ void conv_bias_perm(const float* __restrict__ bif, const float* __restrict__ bhf,
                               const float* __restrict__ bib, const float* __restrict__ bhb,
                               float* __restrict__ o)
{
  int n = blockIdx.x * 256 + threadIdx.x;
  if (n >= NB2) return;
  int d = n / G4, rr = n - d * G4, u = rr >> 2, g = rr & 3;
  int s = g * DD + u;
  o[n] = d ? (bib[s] + bhb[s]) : (bif[s] + bhf[s]);
}

// ---------------- 256x256-tile GEMM (proven R6): phase-interleaved counted-vmcnt ----------------
__global__ __launch_bounds__(512, 1)
void gemm_bt256(const unsigned short* __restrict__ A, int lda,
                const unsigned short* __restrict__ B, int ldb,
                unsigned short* __restrict__ C, int ldc,
                const float* __restrict__ bias, int K)
{
  __shared__ unsigned short lA[2][16384];
  __shared__ unsigned short lB[2][16384];
  const int t = threadIdx.x;
  const int lane = t & 63;
  const int wv = t >> 6;
  const int wm = wv >> 1;
  const int wn = wv & 1;
  const int l15 = lane & 15, q = lane >> 4;
  const long m0 = (long)blockIdx.x * 256;
  const long n0 = (long)blockIdx.y * 256;
  const int rs  = t >> 2;
  const int sc  = (((t & 3) ^ ((t >> 3) & 3))) * 8;
  const int qsw = (q ^ ((l15 >> 1) & 3)) * 8;

  const unsigned short* gA = A + (m0 + rs) * (long)lda + sc;
  const unsigned short* gB = B + (n0 + rs) * (long)ldb + sc;
  const long a128 = (long)128 * lda;
  const long b128 = (long)128 * ldb;

  #define PIECE(b, kt, p, hf) do {                                               \
    const long kb_ = (long)(kt) * 64 + (p) * 32;                                 \
    gl_lds16(gA + kb_ + (hf) * a128, &lA[b][(p) * 8192 + (hf) * 4096 + t * 8]);  \
    gl_lds16(gB + kb_ + (hf) * b128, &lB[b][(p) * 8192 + (hf) * 4096 + t * 8]);  \
  } while (0)

  floatx4 acc[4][8];
  #pragma unroll
  for (int i = 0; i < 4; i++)
    #pragma unroll
    for (int j = 0; j < 8; j++)
      acc[i][j] = (floatx4){0.f, 0.f, 0.f, 0.f};

  PIECE(0, 0, 0, 0); PIECE(0, 0, 0, 1);
  PIECE(0, 0, 1, 0); PIECE(0, 0, 1, 1);

  #pragma unroll 2
  for (int kt = 0; kt < 24; kt++) {
    const int cur = kt & 1;
    const int nxt = cur ^ 1;
    const unsigned short* pA = &lA[cur][0];
    const unsigned short* pB = &lB[cur][0];

    VMCNT(4);
    __builtin_amdgcn_s_barrier();

    #pragma unroll
    for (int ks = 0; ks < 2; ks++) {
      short8 bfr[8];
      #pragma unroll
      for (int ih = 0; ih < 2; ih++) {
        if (kt < 23) {
          if (ks == 0 && ih == 0) PIECE(nxt, kt + 1, 0, 0);
          if (ks == 0 && ih == 1) PIECE(nxt, kt + 1, 0, 1);
          if (ks == 1 && ih == 0) PIECE(nxt, kt + 1, 1, 0);
          if (ks == 1 && ih == 1) PIECE(nxt, kt + 1, 1, 1);
        }
        if (ih == 0) {
          #pragma unroll
          for (int j = 0; j < 8; j++)
            bfr[j] = *(const short8*)(pB + ks * 8192 + (wn * 128 + j * 16 + l15) * 32 + qsw);
        }
        short8 af[2];
        #pragma unroll
        for (int ii = 0; ii < 2; ii++)
          af[ii] = *(const short8*)(pA + ks * 8192 + (wm * 64 + (ih * 2 + ii) * 16 + l15) * 32 + qsw);
        __builtin_amdgcn_s_setprio(1);
        #pragma unroll
        for (int ii = 0; ii < 2; ii++)
          #pragma unroll
          for (int j = 0; j < 8; j++)
            acc[ih * 2 + ii][j] =
              __builtin_amdgcn_mfma_f32_16x16x32_bf16(af[ii], bfr[j], acc[ih * 2 + ii][j], 0, 0, 0);
        __builtin_amdgcn_s_setprio(0);
      }
      if (ks == 0) {
        if (kt < 23) VMCNT(4); else VMCNT(0);
        __builtin_amdgcn_s_barrier();
      }
    }
  }
  #undef PIECE

  #pragma unroll
  for (int i = 0; i < 4; i++) {
    #pragma unroll
    for (int j = 0; j < 8; j++) {
      const long mg = m0 + wm * 64 + i * 16 + q * 4;
      const long ng = n0 + wn * 128 + j * 16 + l15;
      const float bb = bias[ng];
      #pragma unroll
      for (int r = 0; r < 4; r++)
        C[(mg + r) * (long)ldc + ng] = f2bf(acc[i][j][r] + bb);
    }
  }
}

// ---------------- persistent bidirectional LSTM recurrence ----------------
// LOCAL=1 (ndir==2): dependency group (ld,mt) = 24 blocks mapped to ONE XCD
// (group = bid&7, nt = bid>>3; measured bid->XCD round-robin). h exchange is
// XCD-local: plain stores (write-through to local L2) + sc0-only loads (bypass L1,
// read local L2, ~200cy, 23/24 L2-hit). No L3 round-trip, no 24x L3 amplification.
// Barrier stays agent-scope sc1 (sync correctness mapping-independent).
// LOCAL=0 (ndir==1): R5 mapping + sc1 L3-coherent h path.
template<int LOCAL>
__global__ __launch_bounds__(512, 1)
void lstm_persist(const unsigned short* __restrict__ xg, int ldxg,
                  const unsigned short* __restrict__ whh,   // [2][3072][768] permuted
                  unsigned short* __restrict__ hbuf,        // [2][ndir][512][768]
                  unsigned short* __restrict__ outc,        // [16384][1536]
                  unsigned* bar,                            // 8 groups x 16 u32
                  int dir0, int ndir)
{
  __shared__ unsigned short bufA[2][16384];   // dbuf x 4 panels [128][32], swizzled
  __shared__ unsigned short bufB[2][16384];
  __shared__ unsigned short hout[128 * 40];   // h staging, pad 40

  const int bid = blockIdx.x;
  int dm, nt;
  if (LOCAL) { dm = bid & 7; nt = bid >> 3; }            // group per XCD
  else { int xcd = bid & 7; int idx = bid >> 3;
         dm = idx & 3; nt = (idx >> 2) * 8 + xcd; }
  const int ld  = (ndir == 2) ? (dm & 1) : 0;
  const int dir = dir0 + ld;
  const int mt  = (ndir == 2) ? (dm >> 1) : dm;
  const int m0 = mt * 128, n0 = nt * 128;
  const int u0 = n0 >> 2;
  unsigned* gbar = bar + dm * 16;
  const int nb24 = 24;

  const int t0 = threadIdx.x;
  const int lane = t0 & 63;
  const int wv = t0 >> 6;            // 0..7
  const int wm = wv >> 1;            // 0..3 : 32-row band
  const int wn = wv & 1;             // 0..1 : 64-col half
  const int l15 = lane & 15, q = lane >> 4;
  const long ldoff = (ndir == 2 && ld == 1) ? (long)G4 : 0;

  const unsigned short* Bdir = whh + (long)dir * G4 * DD;
  const int srow  = lane >> 2;                               // 0..15
  const int scolA = (((lane & 3) ^ ((lane >> 3) & 3))) * 8;  // staging source slot
  const int qsw   = (q ^ ((l15 >> 1) & 3)) * 8;              // fragment read slot

  const int rb = wv * 16 + srow;                             // staged row 0..127
  const unsigned short* wB  = Bdir + (long)(n0 + rb) * DD + scolA;
  const unsigned short* hA0 = hbuf + ((long)0 * ndir + ld) * ((long)SS * DD) + (long)(m0 + rb) * DD + scolA;
  const unsigned short* hA1 = hbuf + ((long)1 * ndir + ld) * ((long)SS * DD) + (long)(m0 + rb) * DD + scolA;

  float c_reg[2][4];
  #pragma unroll
  for (int i = 0; i < 2; i++)
    #pragma unroll
    for (int j = 0; j < 4; j++)
      c_reg[i][j] = 0.f;

  for (int s = 0; s < BB; s++) {
    const int tt = dir ? (BB - 1 - s) : s;
    const unsigned short* hA = (s & 1) ? hA1 : hA0;
    unsigned short* hw = hbuf + (((long)((s + 1) & 1)) * ndir + ld) * ((long)SS * DD);

    #pragma unroll
    for (int p = 0; p < 4; p++) {
      gl_lds16_h<LOCAL>(hA + p * 32, &bufA[0][p * 4096 + wv * 512 + lane * 8]);
      gl_lds16         (wB + p * 32, &bufB[0][p * 4096 + wv * 512 + lane * 8]);
    }
    shortx4 xr0[4], xr1[4];
    {
      const unsigned short* xb = xg + ((long)tt * SS + m0) * ldxg + ldoff + n0;
      const unsigned short* xb0 = xb + (long)(wm * 32 + l15) * ldxg + wn * 64 + q * 4;
      const unsigned short* xb1 = xb0 + (long)16 * ldxg;
      #pragma unroll
      for (int j = 0; j < 4; j++) {
        xr0[j] = *(const shortx4*)(xb0 + j * 16);
        xr1[j] = *(const shortx4*)(xb1 + j * 16);
      }
    }

    floatx4 acc[2][4];
    #pragma unroll
    for (int i = 0; i < 2; i++)
      #pragma unroll
      for (int j = 0; j < 4; j++)
        acc[i][j] = (floatx4){0.f, 0.f, 0.f, 0.f};

    #pragma unroll
    for (int j6 = 0; j6 < 6; j6++) {
      if (j6 < 5) {
        const int b = (j6 + 1) & 1;
        const long kb = (long)(j6 + 1) * 128;
        #pragma unroll
        for (int p = 0; p < 4; p++) {
          gl_lds16_h<LOCAL>(hA + kb + p * 32, &bufA[b][p * 4096 + wv * 512 + lane * 8]);
          gl_lds16         (wB + kb + p * 32, &bufB[b][p * 4096 + wv * 512 + lane * 8]);
        }
      }
      if (j6 == 0)      VMCNT(16);
      else if (j6 < 5)  VMCNT(8);
      else              VMCNT(0);
      __builtin_amdgcn_s_barrier();
      const int b = j6 & 1;
      __builtin_amdgcn_s_setprio(1);
      #pragma unroll
      for (int ks = 0; ks < 4; ks++) {
        const unsigned short* pA = &bufA[b][ks * 4096];
        const unsigned short* pB = &bufB[b][ks * 4096];
        short8 af[2], bfr[4];
        #pragma unroll
        for (int i = 0; i < 2; i++)
          af[i] = *(const short8*)(pA + (wm * 32 + i * 16 + l15) * 32 + qsw);
        #pragma unroll
        for (int j = 0; j < 4; j++)
          bfr[j] = *(const short8*)(pB + (wn * 64 + j * 16 + l15) * 32 + qsw);
        #pragma unroll
        for (int i = 0; i < 2; i++)
          #pragma unroll
          for (int j = 0; j < 4; j++)
            acc[i][j] = __builtin_amdgcn_mfma_f32_16x16x32_bf16(bfr[j], af[i], acc[i][j], 0, 0, 0);
      }
      __builtin_amdgcn_s_setprio(0);
      if (j6 < 5) __builtin_amdgcn_s_barrier();
    }

    #pragma unroll
    for (int i = 0; i < 2; i++) {
      const int mrow = wm * 32 + i * 16 + l15;
      #pragma unroll
      for (int j = 0; j < 4; j++) {
        const int nb = wn * 64 + j * 16 + q * 4;
        shortx4 xv = i ? xr1[j] : xr0[j];
        float gi = acc[i][j][0] + bf2f((unsigned short)xv[0]);
        float gf = acc[i][j][1] + bf2f((unsigned short)xv[1]);
        float gg = acc[i][j][2] + bf2f((unsigned short)xv[2]);
        float go = acc[i][j][3] + bf2f((unsigned short)xv[3]);
        float c = sigf(gf) * c_reg[i][j] + sigf(gi) * tanhfast(gg);
        float h = sigf(go) * tanhfast(c);
        c_reg[i][j] = c;
        hout[mrow * 40 + (nb >> 2)] = f2bf(h);
      }
    }
    __syncthreads();
    {
      const int row = t0 >> 2;
      const int qq = t0 & 3;
      short8 v0 = *(const short8*)(hout + row * 40 + qq * 8);
      unsigned short* hwp = hw + (long)(m0 + row) * DD + u0 + qq * 8;
      unsigned short* op  = outc + ((long)tt * SS + m0 + row) * IN2 + dir * DD + u0 + qq * 8;
      if (LOCAL) *(short8*)hwp = v0;     // same-XCD consumers: L2 is the coherence point
      else       store16_sc1(hwp, v0);   // cross-XCD consumers: through L3
      *(short8*)op = v0;
    }
    if (s < BB - 1) {
      VMCNT(0);
      __builtin_amdgcn_s_barrier();
      if (threadIdx.x == 0) {
        unsigned g = __hip_atomic_load(gbar + 1, __ATOMIC_RELAXED, __HIP_MEMORY_SCOPE_AGENT);
        unsigned a = __hip_atomic_fetch_add(gbar, 1u, __ATOMIC_RELAXED, __HIP_MEMORY_SCOPE_AGENT);
        if (a == (unsigned)(nb24 - 1)) {
          __hip_atomic_store(gbar, 0u, __ATOMIC_RELAXED, __HIP_MEMORY_SCOPE_AGENT);
          __hip_atomic_store(gbar + 1, g + 1u, __ATOMIC_RELEASE, __HIP_MEMORY_SCOPE_AGENT);
        } else {
          unsigned curv;
          do {
            __builtin_amdgcn_s_sleep(2);
            curv = __hip_atomic_load(gbar + 1, __ATOMIC_RELAXED, __HIP_MEMORY_SCOPE_AGENT);
          } while (curv == g);
        }
      }
      __builtin_amdgcn_s_barrier();
    }
  }
}

// ---------------- final linear [16384,1536](bf16) x [9,1536]^T ----------------
__global__ void final_linear(const unsigned short* __restrict__ xin, const float* __restrict__ w,
                             const float* __restrict__ b, float* __restrict__ out)
{
  __shared__ float red[NCLS * 256];
  int row = blockIdx.x;
  const unsigned short* x = xin + (long)row * IN2;
  float p[NCLS];
  #pragma unroll
  for (int c = 0; c < NCLS; c++) p[c] = 0.f;
  for (int k = threadIdx.x; k < IN2; k += 256) {
    float xv = bf2f(x[k]);
    #pragma unroll
    for (int c = 0; c < NCLS; c++) p[c] += xv * w[c * IN2 + k];
  }
  #pragma unroll
  for (int c = 0; c < NCLS; c++) red[c * 256 + threadIdx.x] = p[c];
  __syncthreads();
  for (int s = 128; s > 0; s >>= 1) {
    if (threadIdx.x < s) {
      #pragma unroll
      for (int c = 0; c < NCLS; c++)
        red[c * 256 + threadIdx.x] += red[c * 256 + threadIdx.x + s];
    }
    __syncthreads();
  }
  if (threadIdx.x < NCLS)
    out[(long)row * NCLS + threadIdx.x] = red[threadIdx.x * 256] + b[threadIdx.x];
}

extern "C" void kernel_launch(void* const* d_in, const int* in_sizes, int n_in,
                              void* d_out, int out_size, void* d_ws, size_t ws_size,
                              hipStream_t stream)
{
  const int*   batch  = (const int*)d_in[0];
  const float* hidden = (const float*)d_in[1];
  const float* w_ih_f = (const float*)d_in[2];
  const float* w_hh_f = (const float*)d_in[3];
  const float* b_ih_f = (const float*)d_in[4];
  const float* b_hh_f = (const float*)d_in[5];
  const float* w_ih_b = (const float*)d_in[6];
  const float* w_hh_b = (const float*)d_in[7];
  const float* b_ih_b = (const float*)d_in[8];
  const float* b_hh_b = (const float*)d_in[9];
  const float* lin_w  = (const float*)d_in[10];
  const float* lin_b  = (const float*)d_in[11];
  float* out = (float*)d_out;

  char* ws = (char*)d_ws;
  size_t off = 0;
  auto alloc = [&](size_t bytes) -> char* {
    char* p = ws + off;
    off += (bytes + 255) & ~(size_t)255;
    return p;
  };

  const size_t SZ_XG_A = (size_t)ROWS * NB2 * 2;      // 201.3 MB
  const size_t SZ_XG_B = (size_t)ROWS * G4  * 2;      // 100.7 MB
  const size_t SZ_XBF  = (size_t)ROWS * IN2 * 2;      //  50.3 MB
  const size_t SZ_W    = (size_t)G4 * IN2 * 2;        //   9.4 MB
  const size_t SZ_BIAS = (size_t)NB2 * 4;
  const size_t SZ_HBUF = (size_t)2 * 2 * SS * DD * 2; //   3.1 MB
  const size_t SZ_BAR  = 512;
  const size_t SZ_SUMS = (size_t)VOCAB * DD * 4 + (size_t)VOCAB * 4;

  const size_t NEED_C = SZ_XG_A + SZ_XBF + SZ_W + SZ_BIAS + SZ_HBUF + SZ_BAR + 8 * 256;
  const bool combined = ws_size >= NEED_C;

  const long nWIH = (long)G4 * IN2;
  const long nWHH = (long)G4 * DD;

  if (combined) {
    unsigned short* xg   = (unsigned short*)alloc(SZ_XG_A);
    unsigned short* xbf  = (unsigned short*)alloc(SZ_XBF);   // x input, later reused as outc
    unsigned short* wbuf = (unsigned short*)alloc(SZ_W);     // wih_f -> wih_b -> whh(both)
    float*          bias = (float*)alloc(SZ_BIAS);
    unsigned short* hbuf = (unsigned short*)alloc(SZ_HBUF);
    unsigned*       bar  = (unsigned*)alloc(SZ_BAR);
    float* sums   = (float*)xg;                              // overlay, consumed pre-xg-GEMM
    float* counts = sums + (size_t)VOCAB * DD;

    hipMemsetAsync(sums, 0, SZ_SUMS, stream);
    hipMemsetAsync(bar, 0, SZ_BAR, stream);
    seg_scatter<<<ROWS, 256, 0, stream>>>(batch, hidden, sums, counts);
    build_x<<<ROWS, 256, 0, stream>>>(batch, hidden, sums, counts, xbf);
    conv_bias_perm<<<(NB2 + 255) / 256, 256, 0, stream>>>(b_ih_f, b_hh_f, b_ih_b, b_hh_b, bias);

    for (int dir = 0; dir < 2; dir++) {
      conv_w_perm<<<(unsigned)((nWIH + 255) / 256), 256, 0, stream>>>(dir ? w_ih_b : w_ih_f, wbuf, IN2);
      dim3 grid(ROWS / 256, G4 / 256, 1);
      gemm_bt256<<<grid, 512, 0, stream>>>(xbf, IN2, wbuf, IN2,
                                           xg + (size_t)dir * G4, NB2,
                                           bias + (size_t)dir * G4, IN2);
    }
    conv_w_perm<<<(unsigned)((nWHH + 255) / 256), 256, 0, stream>>>(w_hh_f, wbuf, DD);
    conv_w_perm<<<(unsigned)((nWHH + 255) / 256), 256, 0, stream>>>(w_hh_b, wbuf + (size_t)G4 * DD, DD);

    hipMemsetAsync(hbuf, 0, SZ_HBUF, stream);
    lstm_persist<1><<<192, 512, 0, stream>>>(xg, NB2, wbuf, hbuf, xbf, bar, 0, 2);
    final_linear<<<ROWS, 256, 0, stream>>>(xbf, lin_w, lin_b, out);
  } else {
    // direction-sequential (~223 MB, proven to fit)
    unsigned short* xg   = (unsigned short*)alloc(SZ_XG_B);
    unsigned short* xbf  = (unsigned short*)alloc(SZ_XBF);
    unsigned short* outc = (unsigned short*)alloc(SZ_XBF);
    unsigned short* wih  = (unsigned short*)alloc(SZ_W);
    unsigned short* whh  = (unsigned short*)alloc(SZ_W);
    float*          bias = (float*)alloc(SZ_BIAS);
    unsigned short* hbuf = (unsigned short*)alloc(SZ_HBUF);
    unsigned*       bar  = (unsigned*)alloc(SZ_BAR);
    float* sums   = (float*)xg;
    float* counts = sums + (size_t)VOCAB * DD;

    hipMemsetAsync(sums, 0, SZ_SUMS, stream);
    hipMemsetAsync(bar, 0, SZ_BAR, stream);
    seg_scatter<<<ROWS, 256, 0, stream>>>(batch, hidden, sums, counts);
    build_x<<<ROWS, 256, 0, stream>>>(batch, hidden, sums, counts, xbf);
    conv_bias_perm<<<(NB2 + 255) / 256, 256, 0, stream>>>(b_ih_f, b_hh_f, b_ih_b, b_hh_b, bias);
    conv_w_perm<<<(unsigned)((nWHH + 255) / 256), 256, 0, stream>>>(w_hh_f, whh, DD);
    conv_w_perm<<<(unsigned)((nWHH + 255) / 256), 256, 0, stream>>>(w_hh_b, whh + (size_t)G4 * DD, DD);

    for (int dir = 0; dir < 2; dir++) {
      conv_w_perm<<<(unsigned)((nWIH + 255) / 256), 256, 0, stream>>>(dir ? w_ih_b : w_ih_f, wih, IN2);
      {
        dim3 grid(ROWS / 256, G4 / 256, 1);
        gemm_bt256<<<grid, 512, 0, stream>>>(xbf, IN2, wih, IN2, xg, G4,
                                             bias + (size_t)dir * G4, IN2);
      }
      hipMemsetAsync(hbuf, 0, SZ_HBUF, stream);
      lstm_persist<0><<<96, 512, 0, stream>>>(xg, G4, whh, hbuf, outc, bar, dir, 1);
    }
    final_linear<<<ROWS, 256, 0, stream>>>(outc, lin_w, lin_b, out);
  }
}

// Round 9
// 1110.617 us; speedup vs baseline: 1.1118x; 1.0227x over previous
//
#include <hip/hip_runtime.h>

#define VOCAB 28996
#define BB 32
#define SS 512
#define DD 768
#define NCLS 9
#define ROWS (BB*SS)     // 16384
#define IN2 (2*DD)       // 1536
#define G4 (4*DD)        // 3072
#define NB2 (2*G4)       // 6144

typedef __attribute__((ext_vector_type(8))) short short8;
typedef __attribute__((ext_vector_type(4))) short shortx4;
typedef __attribute__((ext_vector_type(4))) float floatx4;
typedef unsigned long long ull;

__device__ __forceinline__ float bf2f(unsigned short u){
  union { unsigned int i; float f; } v; v.i = ((unsigned int)u) << 16; return v.f;
}
__device__ __forceinline__ unsigned short f2bf(float f){
  union { float f; unsigned int i; } v; v.f = f;
  unsigned int r = v.i + 0x7FFFu + ((v.i >> 16) & 1u);
  return (unsigned short)(r >> 16);
}
__device__ __forceinline__ float sigf(float x){ return 1.0f / (1.0f + __expf(-x)); }
__device__ __forceinline__ float tanhfast(float x){
  float y = fminf(fmaxf(x, -15.f), 15.f);
  float e = __expf(2.f * y);
  return 1.f - 2.f / (e + 1.f);
}

__device__ __forceinline__ void gl_lds16(const unsigned short* g, unsigned short* l){
  __builtin_amdgcn_global_load_lds((__attribute__((address_space(1))) void*)(g),
                                   (__attribute__((address_space(3))) void*)(l), 16, 0, 0);
}
// h-path load, parameterized coherence:
// LOCAL=1: sc0 only -> bypass L1, read the block's own XCD L2 (producers same-XCD)
// LOCAL=0: sc0|sc1  -> bypass L1+L2, read memory-side L3 (producers cross-XCD)
template<int LOCAL>
__device__ __forceinline__ void gl_lds16_h(const unsigned short* g, unsigned short* l){
  __builtin_amdgcn_global_load_lds((__attribute__((address_space(1))) void*)(g),
                                   (__attribute__((address_space(3))) void*)(l), 16, 0,
                                   LOCAL ? 1 : 17);
}
// write-through store to the coherence point (L3) so sc1 readers on other XCDs see it
__device__ __forceinline__ void store16_sc1(unsigned short* p, short8 v){
  asm volatile("global_store_dwordx4 %0, %1, off sc0 sc1" :: "v"(p), "v"(v) : "memory");
}

#define VMCNT(n) do { asm volatile("s_waitcnt vmcnt(" #n ")" ::: "memory"); \
                      __builtin_amdgcn_sched_barrier(0); } while (0)

// ---------------- segment mean ----------------
__global__ void seg_scatter(const int* __restrict__ ids, const float* __restrict__ hidden,
                            float* __restrict__ sums, float* __restrict__ counts)
{
  int r = blockIdx.x;
  int id = ids[r];
  const float* h = hidden + (long)r * DD;
  float* s = sums + (long)id * DD;
  for (int d = threadIdx.x; d < DD; d += 256)
    atomicAdd(&s[d], h[d]);
  if (threadIdx.x == 0) atomicAdd(&counts[id], 1.0f);
}

__global__ void build_x(const int* __restrict__ ids, const float* __restrict__ hidden,
                        const float* __restrict__ sums, const float* __restrict__ counts,
                        unsigned short* __restrict__ x)
{
  int r = blockIdx.x;
  int id = ids[r];
  float inv = 1.0f / fmaxf(counts[id], 1.0f);
  const float* h = hidden + (long)r * DD;
  const float* s = sums + (long)id * DD;
  unsigned short* xr = x + (long)r * IN2;
  for (int d = threadIdx.x; d < DD; d += 256) {
    xr[d]      = f2bf(h[d]);
    xr[DD + d] = f2bf(s[d] * inv);
  }
}

// -------- weight conversion with gate-interleave permutation: row' = u*4+g <- row g*768+u --------
__global__ void conv_w_perm(const float* __restrict__ w, unsigned short* __restrict__ o, int K)
{
  long i = (long)blockIdx.x * 256 + threadIdx.x;
  if (i >= (long)G4 * K) return;
  int row = (int)(i / K); int k = (int)(i - (long)row * K);
  int u = row >> 2, g = row & 3;
  o[i] = f2bf(w[((long)(g * DD + u)) * K + k]);
}

__global__ void conv_bias_perm(const float* __restrict__ bif, const float* __restrict__ bhf,
                               const float* __restrict__ bib, const float* __restrict__ bhb,
                               float* __restrict__ o)
{
  int n = blockIdx.x * 256 + threadIdx.x;
  if (n >= NB2) return;
  int d = n / G4, rr = n - d * G4, u = rr >> 2, g = rr & 3;
  int s = g * DD + u;
  o[n] = d ? (bib[s] + bhb[s]) : (bif[s] + bhf[s]);
}

// ---------------- 256x256-tile GEMM (proven R6): phase-interleaved counted-vmcnt ----------------
__global__ __launch_bounds__(512, 1)
void gemm_bt256(const unsigned short* __restrict__ A, int lda,
                const unsigned short* __restrict__ B, int ldb,
                unsigned short* __restrict__ C, int ldc,
                const float* __restrict__ bias, int K)
{
  __shared__ unsigned short lA[2][16384];
  __shared__ unsigned short lB[2][16384];
  const int t = threadIdx.x;
  const int lane = t & 63;
  const int wv = t >> 6;
  const int wm = wv >> 1;
  const int wn = wv & 1;
  const int l15 = lane & 15, q = lane >> 4;
  const long m0 = (long)blockIdx.x * 256;
  const long n0 = (long)blockIdx.y * 256;
  const int rs  = t >> 2;
  const int sc  = (((t & 3) ^ ((t >> 3) & 3))) * 8;
  const int qsw = (q ^ ((l15 >> 1) & 3)) * 8;

  const unsigned short* gA = A + (m0 + rs) * (long)lda + sc;
  const unsigned short* gB = B + (n0 + rs) * (long)ldb + sc;
  const long a128 = (long)128 * lda;
  const long b128 = (long)128 * ldb;

  #define PIECE(b, kt, p, hf) do {                                               \
    const long kb_ = (long)(kt) * 64 + (p) * 32;                                 \
    gl_lds16(gA + kb_ + (hf) * a128, &lA[b][(p) * 8192 + (hf) * 4096 + t * 8]);  \
    gl_lds16(gB + kb_ + (hf) * b128, &lB[b][(p) * 8192 + (hf) * 4096 + t * 8]);  \
  } while (0)

  floatx4 acc[4][8];
  #pragma unroll
  for (int i = 0; i < 4; i++)
    #pragma unroll
    for (int j = 0; j < 8; j++)
      acc[i][j] = (floatx4){0.f, 0.f, 0.f, 0.f};

  PIECE(0, 0, 0, 0); PIECE(0, 0, 0, 1);
  PIECE(0, 0, 1, 0); PIECE(0, 0, 1, 1);

  #pragma unroll 2
  for (int kt = 0; kt < 24; kt++) {
    const int cur = kt & 1;
    const int nxt = cur ^ 1;
    const unsigned short* pA = &lA[cur][0];
    const unsigned short* pB = &lB[cur][0];

    VMCNT(4);
    __builtin_amdgcn_s_barrier();

    #pragma unroll
    for (int ks = 0; ks < 2; ks++) {
      short8 bfr[8];
      #pragma unroll
      for (int ih = 0; ih < 2; ih++) {
        if (kt < 23) {
          if (ks == 0 && ih == 0) PIECE(nxt, kt + 1, 0, 0);
          if (ks == 0 && ih == 1) PIECE(nxt, kt + 1, 0, 1);
          if (ks == 1 && ih == 0) PIECE(nxt, kt + 1, 1, 0);
          if (ks == 1 && ih == 1) PIECE(nxt, kt + 1, 1, 1);
        }
        if (ih == 0) {
          #pragma unroll
          for (int j = 0; j < 8; j++)
            bfr[j] = *(const short8*)(pB + ks * 8192 + (wn * 128 + j * 16 + l15) * 32 + qsw);
        }
        short8 af[2];
        #pragma unroll
        for (int ii = 0; ii < 2; ii++)
          af[ii] = *(const short8*)(pA + ks * 8192 + (wm * 64 + (ih * 2 + ii) * 16 + l15) * 32 + qsw);
        __builtin_amdgcn_s_setprio(1);
        #pragma unroll
        for (int ii = 0; ii < 2; ii++)
          #pragma unroll
          for (int j = 0; j < 8; j++)
            acc[ih * 2 + ii][j] =
              __builtin_amdgcn_mfma_f32_16x16x32_bf16(af[ii], bfr[j], acc[ih * 2 + ii][j], 0, 0, 0);
        __builtin_amdgcn_s_setprio(0);
      }
      if (ks == 0) {
        if (kt < 23) VMCNT(4); else VMCNT(0);
        __builtin_amdgcn_s_barrier();
      }
    }
  }
  #undef PIECE

  #pragma unroll
  for (int i = 0; i < 4; i++) {
    #pragma unroll
    for (int j = 0; j < 8; j++) {
      const long mg = m0 + wm * 64 + i * 16 + q * 4;
      const long ng = n0 + wn * 128 + j * 16 + l15;
      const float bb = bias[ng];
      #pragma unroll
      for (int r = 0; r < 4; r++)
        C[(mg + r) * (long)ldc + ng] = f2bf(acc[i][j][r] + bb);
    }
  }
}

// ---------------- persistent bidirectional LSTM recurrence ----------------
// R7 XCD-local mapping kept (group = bid&7 -> one XCD; h via local L2). New k-loop:
// K=64 tiles (12/step), TRIPLE-buffered, prefetch distance 2 (stage j+2 during
// compute j) -- ~2300cy coverage vs ~900cy L3 whh latency (whh can't stay L2-resident:
// 4.7MB/XCD > 4MB). whh tiles 0,1 of step s+1 prefetched BEFORE the group barrier
// (weights static). xg loads / outc stores non-temporal (stop evicting whh/hbuf).
// vmcnt ledger (per wave, 4 instr/tile, in-order retire):
//   step top outstanding: Bpre0(2) Bpre1(2) xg(8) A0(2) A1(2)
//   j=0: VMCNT(2)  j=1..10: VMCNT(4)  j=11: VMCNT(0)
template<int LOCAL>
__global__ __launch_bounds__(512, 1)
void lstm_persist(const unsigned short* __restrict__ xg, int ldxg,
                  const unsigned short* __restrict__ whh,   // [2][3072][768] permuted
                  unsigned short* __restrict__ hbuf,        // [2][ndir][512][768]
                  unsigned short* __restrict__ outc,        // [16384][1536]
                  unsigned* bar,                            // 8 groups x 16 u32
                  int dir0, int ndir)
{
  __shared__ unsigned short bufA[3][8192];    // 3 tiles x 2 panels [128][32], swizzled
  __shared__ unsigned short bufB[3][8192];
  __shared__ unsigned short hout[128 * 40];   // h staging, pad 40

  const int bid = blockIdx.x;
  int dm, nt;
  if (LOCAL) { dm = bid & 7; nt = bid >> 3; }            // group per XCD
  else { int xcd = bid & 7; int idx = bid >> 3;
         dm = idx & 3; nt = (idx >> 2) * 8 + xcd; }
  const int ld  = (ndir == 2) ? (dm & 1) : 0;
  const int dir = dir0 + ld;
  const int mt  = (ndir == 2) ? (dm >> 1) : dm;
  const int m0 = mt * 128, n0 = nt * 128;
  const int u0 = n0 >> 2;
  unsigned* gbar = bar + dm * 16;
  const int nb24 = 24;

  const int t0 = threadIdx.x;
  const int lane = t0 & 63;
  const int wv = t0 >> 6;            // 0..7
  const int wm = wv >> 1;            // 0..3 : 32-row band
  const int wn = wv & 1;             // 0..1 : 64-col half
  const int l15 = lane & 15, q = lane >> 4;
  const long ldoff = (ndir == 2 && ld == 1) ? (long)G4 : 0;

  const unsigned short* Bdir = whh + (long)dir * G4 * DD;
  const int srow  = lane >> 2;                               // 0..15
  const int scolA = (((lane & 3) ^ ((lane >> 3) & 3))) * 8;  // staging source slot
  const int qsw   = (q ^ ((l15 >> 1) & 3)) * 8;              // fragment read slot

  const int rb = wv * 16 + srow;                             // staged row 0..127
  const unsigned short* wB  = Bdir + (long)(n0 + rb) * DD + scolA;
  const unsigned short* hA0 = hbuf + ((long)0 * ndir + ld) * ((long)SS * DD) + (long)(m0 + rb) * DD + scolA;
  const unsigned short* hA1 = hbuf + ((long)1 * ndir + ld) * ((long)SS * DD) + (long)(m0 + rb) * DD + scolA;

  // per-wave staging: 2 instr per matrix per K=64 tile (2 panels of [128][32])
  #define STAGE_B(j, b) do { const long kb_ = (long)(j) * 64;                 \
    gl_lds16(wB + kb_,      &bufB[b][wv * 512 + lane * 8]);                   \
    gl_lds16(wB + kb_ + 32, &bufB[b][4096 + wv * 512 + lane * 8]); } while (0)
  #define STAGE_A(j, b) do { const long kb_ = (long)(j) * 64;                 \
    gl_lds16_h<LOCAL>(hA + kb_,      &bufA[b][wv * 512 + lane * 8]);          \
    gl_lds16_h<LOCAL>(hA + kb_ + 32, &bufA[b][4096 + wv * 512 + lane * 8]); } while (0)

  float c_reg[2][4];
  #pragma unroll
  for (int i = 0; i < 2; i++)
    #pragma unroll
    for (int j = 0; j < 4; j++)
      c_reg[i][j] = 0.f;

  for (int s = 0; s < BB; s++) {
    const int tt = dir ? (BB - 1 - s) : s;
    const unsigned short* hA = (s & 1) ? hA1 : hA0;
    unsigned short* hw = hbuf + (((long)((s + 1) & 1)) * ndir + ld) * ((long)SS * DD);

    // ---- step prologue. Steady state: B tiles 0,1 already prefetched pre-barrier.
    if (s == 0) { STAGE_B(0, 0); STAGE_B(1, 1); }
    shortx4 xr0[4], xr1[4];
    {
      const unsigned short* xb = xg + ((long)tt * SS + m0) * ldxg + ldoff + n0;
      const unsigned short* xb0 = xb + (long)(wm * 32 + l15) * ldxg + wn * 64 + q * 4;
      const unsigned short* xb1 = xb0 + (long)16 * ldxg;
      #pragma unroll
      for (int jj = 0; jj < 4; jj++) {
        xr0[jj] = __builtin_nontemporal_load((const shortx4*)(xb0 + jj * 16));
        xr1[jj] = __builtin_nontemporal_load((const shortx4*)(xb1 + jj * 16));
      }
    }
    STAGE_A(0, 0);
    STAGE_A(1, 1);

    floatx4 acc[2][4];
    #pragma unroll
    for (int i = 0; i < 2; i++)
      #pragma unroll
      for (int j = 0; j < 4; j++)
        acc[i][j] = (floatx4){0.f, 0.f, 0.f, 0.f};

    // ---- 12 K=64 tiles, triple-buffered, distance-2, counted vmcnt ----
    #pragma unroll
    for (int j12 = 0; j12 < 12; j12++) {
      if (j12 == 0)       VMCNT(2);   // tile0 (Bpre+A0) landed; A1 in flight
      else if (j12 < 11)  VMCNT(4);   // tile j landed; stage(j+1) in flight
      else                VMCNT(0);   // tile11 landed
      __builtin_amdgcn_s_barrier();
      if (j12 < 10) {                 // stage tile j+2 (overwrites buf read in j-1: safe)
        const int bn = (j12 + 2) % 3;
        STAGE_B(j12 + 2, bn);         // B first: longest latency
        STAGE_A(j12 + 2, bn);
      }
      const int b = j12 % 3;
      __builtin_amdgcn_s_setprio(1);
      #pragma unroll
      for (int ks = 0; ks < 2; ks++) {
        const unsigned short* pA = &bufA[b][ks * 4096];
        const unsigned short* pB = &bufB[b][ks * 4096];
        short8 af[2], bfr[4];
        #pragma unroll
        for (int i = 0; i < 2; i++)
          af[i] = *(const short8*)(pA + (wm * 32 + i * 16 + l15) * 32 + qsw);
        #pragma unroll
        for (int j = 0; j < 4; j++)
          bfr[j] = *(const short8*)(pB + (wn * 64 + j * 16 + l15) * 32 + qsw);
        #pragma unroll
        for (int i = 0; i < 2; i++)
          #pragma unroll
          for (int j = 0; j < 4; j++)
            acc[i][j] = __builtin_amdgcn_mfma_f32_16x16x32_bf16(bfr[j], af[i], acc[i][j], 0, 0, 0);
      }
      __builtin_amdgcn_s_setprio(0);
    }

    // ---- zero-shuffle gate epilogue (xg from registers) ----
    #pragma unroll
    for (int i = 0; i < 2; i++) {
      const int mrow = wm * 32 + i * 16 + l15;
      #pragma unroll
      for (int j = 0; j < 4; j++) {
        const int nb = wn * 64 + j * 16 + q * 4;
        shortx4 xv = i ? xr1[j] : xr0[j];
        float gi = acc[i][j][0] + bf2f((unsigned short)xv[0]);
        float gf = acc[i][j][1] + bf2f((unsigned short)xv[1]);
        float gg = acc[i][j][2] + bf2f((unsigned short)xv[2]);
        float go = acc[i][j][3] + bf2f((unsigned short)xv[3]);
        float c = sigf(gf) * c_reg[i][j] + sigf(gi) * tanhfast(gg);
        float h = sigf(go) * tanhfast(c);
        c_reg[i][j] = c;
        hout[mrow * 40 + (nb >> 2)] = f2bf(h);
      }
    }
    __syncthreads();
    {
      const int row = t0 >> 2;
      const int qq = t0 & 3;
      short8 v0 = *(const short8*)(hout + row * 40 + qq * 8);
      unsigned short* hwp = hw + (long)(m0 + row) * DD + u0 + qq * 8;
      unsigned short* op  = outc + ((long)tt * SS + m0 + row) * IN2 + dir * DD + u0 + qq * 8;
      if (LOCAL) *(short8*)hwp = v0;     // same-XCD consumers: L2 is the coherence point
      else       store16_sc1(hwp, v0);   // cross-XCD consumers: through L3
      __builtin_nontemporal_store(v0, (short8*)op);
    }
    if (s < BB - 1) {
      VMCNT(0);                          // only the 2 epilogue stores outstanding
      __builtin_amdgcn_s_barrier();      // all waves' stores drained
      STAGE_B(0, 0);                     // prefetch next step's whh tiles across the barrier
      STAGE_B(1, 1);                     // (static data; hides L3 latency at pipeline fill)
      if (threadIdx.x == 0) {
        unsigned g = __hip_atomic_load(gbar + 1, __ATOMIC_RELAXED, __HIP_MEMORY_SCOPE_AGENT);
        unsigned a = __hip_atomic_fetch_add(gbar, 1u, __ATOMIC_RELAXED, __HIP_MEMORY_SCOPE_AGENT);
        if (a == (unsigned)(nb24 - 1)) {
          __hip_atomic_store(gbar, 0u, __ATOMIC_RELAXED, __HIP_MEMORY_SCOPE_AGENT);
          __hip_atomic_store(gbar + 1, g + 1u, __ATOMIC_RELEASE, __HIP_MEMORY_SCOPE_AGENT);
        } else {
          unsigned curv;
          do {
            __builtin_amdgcn_s_sleep(2);
            curv = __hip_atomic_load(gbar + 1, __ATOMIC_RELAXED, __HIP_MEMORY_SCOPE_AGENT);
          } while (curv == g);
        }
      }
      __builtin_amdgcn_s_barrier();
    }
  }
  #undef STAGE_A
  #undef STAGE_B
}

// ---------------- final linear [16384,1536](bf16) x [9,1536]^T ----------------
__global__ void final_linear(const unsigned short* __restrict__ xin, const float* __restrict__ w,
                             const float* __restrict__ b, float* __restrict__ out)
{
  __shared__ float red[NCLS * 256];
  int row = blockIdx.x;
  const unsigned short* x = xin + (long)row * IN2;
  float p[NCLS];
  #pragma unroll
  for (int c = 0; c < NCLS; c++) p[c] = 0.f;
  for (int k = threadIdx.x; k < IN2; k += 256) {
    float xv = bf2f(x[k]);
    #pragma unroll
    for (int c = 0; c < NCLS; c++) p[c] += xv * w[c * IN2 + k];
  }
  #pragma unroll
  for (int c = 0; c < NCLS; c++) red[c * 256 + threadIdx.x] = p[c];
  __syncthreads();
  for (int s = 128; s > 0; s >>= 1) {
    if (threadIdx.x < s) {
      #pragma unroll
      for (int c = 0; c < NCLS; c++)
        red[c * 256 + threadIdx.x] += red[c * 256 + threadIdx.x + s];
    }
    __syncthreads();
  }
  if (threadIdx.x < NCLS)
    out[(long)row * NCLS + threadIdx.x] = red[threadIdx.x * 256] + b[threadIdx.x];
}

extern "C" void kernel_launch(void* const* d_in, const int* in_sizes, int n_in,
                              void* d_out, int out_size, void* d_ws, size_t ws_size,
                              hipStream_t stream)
{
  const int*   batch  = (const int*)d_in[0];
  const float* hidden = (const float*)d_in[1];
  const float* w_ih_f = (const float*)d_in[2];
  const float* w_hh_f = (const float*)d_in[3];
  const float* b_ih_f = (const float*)d_in[4];
  const float* b_hh_f = (const float*)d_in[5];
  const float* w_ih_b = (const float*)d_in[6];
  const float* w_hh_b = (const float*)d_in[7];
  const float* b_ih_b = (const float*)d_in[8];
  const float* b_hh_b = (const float*)d_in[9];
  const float* lin_w  = (const float*)d_in[10];
  const float* lin_b  = (const float*)d_in[11];
  float* out = (float*)d_out;

  char* ws = (char*)d_ws;
  size_t off = 0;
  auto alloc = [&](size_t bytes) -> char* {
    char* p = ws + off;
    off += (bytes + 255) & ~(size_t)255;
    return p;
  };

  const size_t SZ_XG_A = (size_t)ROWS * NB2 * 2;      // 201.3 MB
  const size_t SZ_XG_B = (size_t)ROWS * G4  * 2;      // 100.7 MB
  const size_t SZ_XBF  = (size_t)ROWS * IN2 * 2;      //  50.3 MB
  const size_t SZ_W    = (size_t)G4 * IN2 * 2;        //   9.4 MB
  const size_t SZ_BIAS = (size_t)NB2 * 4;
  const size_t SZ_HBUF = (size_t)2 * 2 * SS * DD * 2; //   3.1 MB
  const size_t SZ_BAR  = 512;
  const size_t SZ_SUMS = (size_t)VOCAB * DD * 4 + (size_t)VOCAB * 4;

  const size_t NEED_C = SZ_XG_A + SZ_XBF + SZ_W + SZ_BIAS + SZ_HBUF + SZ_BAR + 8 * 256;
  const bool combined = ws_size >= NEED_C;

  const long nWIH = (long)G4 * IN2;
  const long nWHH = (long)G4 * DD;

  if (combined) {
    unsigned short* xg   = (unsigned short*)alloc(SZ_XG_A);
    unsigned short* xbf  = (unsigned short*)alloc(SZ_XBF);   // x input, later reused as outc
    unsigned short* wbuf = (unsigned short*)alloc(SZ_W);     // wih_f -> wih_b -> whh(both)
    float*          bias = (float*)alloc(SZ_BIAS);
    unsigned short* hbuf = (unsigned short*)alloc(SZ_HBUF);
    unsigned*       bar  = (unsigned*)alloc(SZ_BAR);
    float* sums   = (float*)xg;                              // overlay, consumed pre-xg-GEMM
    float* counts = sums + (size_t)VOCAB * DD;

    hipMemsetAsync(sums, 0, SZ_SUMS, stream);
    hipMemsetAsync(bar, 0, SZ_BAR, stream);
    seg_scatter<<<ROWS, 256, 0, stream>>>(batch, hidden, sums, counts);
    build_x<<<ROWS, 256, 0, stream>>>(batch, hidden, sums, counts, xbf);
    conv_bias_perm<<<(NB2 + 255) / 256, 256, 0, stream>>>(b_ih_f, b_hh_f, b_ih_b, b_hh_b, bias);

    for (int dir = 0; dir < 2; dir++) {
      conv_w_perm<<<(unsigned)((nWIH + 255) / 256), 256, 0, stream>>>(dir ? w_ih_b : w_ih_f, wbuf, IN2);
      dim3 grid(ROWS / 256, G4 / 256, 1);
      gemm_bt256<<<grid, 512, 0, stream>>>(xbf, IN2, wbuf, IN2,
                                           xg + (size_t)dir * G4, NB2,
                                           bias + (size_t)dir * G4, IN2);
    }
    conv_w_perm<<<(unsigned)((nWHH + 255) / 256), 256, 0, stream>>>(w_hh_f, wbuf, DD);
    conv_w_perm<<<(unsigned)((nWHH + 255) / 256), 256, 0, stream>>>(w_hh_b, wbuf + (size_t)G4 * DD, DD);

    hipMemsetAsync(hbuf, 0, SZ_HBUF, stream);
    lstm_persist<1><<<192, 512, 0, stream>>>(xg, NB2, wbuf, hbuf, xbf, bar, 0, 2);
    final_linear<<<ROWS, 256, 0, stream>>>(xbf, lin_w, lin_b, out);
  } else {
    // direction-sequential (~223 MB, proven to fit)
    unsigned short* xg   = (unsigned short*)alloc(SZ_XG_B);
    unsigned short* xbf  = (unsigned short*)alloc(SZ_XBF);
    unsigned short* outc = (unsigned short*)alloc(SZ_XBF);
    unsigned short* wih  = (unsigned short*)alloc(SZ_W);
    unsigned short* whh  = (unsigned short*)alloc(SZ_W);
    float*          bias = (float*)alloc(SZ_BIAS);
    unsigned short* hbuf = (unsigned short*)alloc(SZ_HBUF);
    unsigned*       bar  = (unsigned*)alloc(SZ_BAR);
    float* sums   = (float*)xg;
    float* counts = sums + (size_t)VOCAB * DD;

    hipMemsetAsync(sums, 0, SZ_SUMS, stream);
    hipMemsetAsync(bar, 0, SZ_BAR, stream);
    seg_scatter<<<ROWS, 256, 0, stream>>>(batch, hidden, sums, counts);
    build_x<<<ROWS, 256, 0, stream>>>(batch, hidden, sums, counts, xbf);
    conv_bias_perm<<<(NB2 + 255) / 256, 256, 0, stream>>>(b_ih_f, b_hh_f, b_ih_b, b_hh_b, bias);
    conv_w_perm<<<(unsigned)((nWHH + 255) / 256), 256, 0, stream>>>(w_hh_f, whh, DD);
    conv_w_perm<<<(unsigned)((nWHH + 255) / 256), 256, 0, stream>>>(w_hh_b, whh + (size_t)G4 * DD, DD);

    for (int dir = 0; dir < 2; dir++) {
      conv_w_perm<<<(unsigned)((nWIH + 255) / 256), 256, 0, stream>>>(dir ? w_ih_b : w_ih_f, wih, IN2);
      {
        dim3 grid(ROWS / 256, G4 / 256, 1);
        gemm_bt256<<<grid, 512, 0, stream>>>(xbf, IN2, wih, IN2, xg, G4,
                                             bias + (size_t)dir * G4, IN2);
      }
      hipMemsetAsync(hbuf, 0, SZ_HBUF, stream);
      lstm_persist<0><<<96, 512, 0, stream>>>(xg, G4, whh, hbuf, outc, bar, dir, 1);
    }
    final_linear<<<ROWS, 256, 0, stream>>>(outc, lin_w, lin_b, out);
  }
}

// Round 11
// 1098.312 us; speedup vs baseline: 1.1243x; 1.0112x over previous
//
#include <hip/hip_runtime.h>

#define VOCAB 28996
#define BB 32
#define SS 512
#define DD 768
#define NCLS 9
#define ROWS (BB*SS)     // 16384
#define IN2 (2*DD)       // 1536
#define G4 (4*DD)        // 3072
#define NB2 (2*G4)       // 6144

typedef __attribute__((ext_vector_type(8))) short short8;
typedef __attribute__((ext_vector_type(4))) short shortx4;
typedef __attribute__((ext_vector_type(4))) float floatx4;
typedef unsigned long long ull;

__device__ __forceinline__ float bf2f(unsigned short u){
  union { unsigned int i; float f; } v; v.i = ((unsigned int)u) << 16; return v.f;
}
__device__ __forceinline__ unsigned short f2bf(float f){
  union { float f; unsigned int i; } v; v.f = f;
  unsigned int r = v.i + 0x7FFFu + ((v.i >> 16) & 1u);
  return (unsigned short)(r >> 16);
}
__device__ __forceinline__ float sigf(float x){ return 1.0f / (1.0f + __expf(-x)); }
__device__ __forceinline__ float tanhfast(float x){
  float y = fminf(fmaxf(x, -15.f), 15.f);
  float e = __expf(2.f * y);
  return 1.f - 2.f / (e + 1.f);
}

__device__ __forceinline__ void gl_lds16(const unsigned short* g, unsigned short* l){
  __builtin_amdgcn_global_load_lds((__attribute__((address_space(1))) void*)(g),
                                   (__attribute__((address_space(3))) void*)(l), 16, 0, 0);
}
// h-path load, parameterized coherence:
// LOCAL=1: sc0 only -> bypass L1, read the block's own XCD L2 (producers same-XCD)
// LOCAL=0: sc0|sc1  -> bypass L1+L2, read memory-side L3 (producers cross-XCD)
template<int LOCAL>
__device__ __forceinline__ void gl_lds16_h(const unsigned short* g, unsigned short* l){
  __builtin_amdgcn_global_load_lds((__attribute__((address_space(1))) void*)(g),
                                   (__attribute__((address_space(3))) void*)(l), 16, 0,
                                   LOCAL ? 1 : 17);
}
// write-through store to the coherence point (L3) so sc1 readers on other XCDs see it
__device__ __forceinline__ void store16_sc1(unsigned short* p, short8 v){
  asm volatile("global_store_dwordx4 %0, %1, off sc0 sc1" :: "v"(p), "v"(v) : "memory");
}

#define VMCNT(n) do { asm volatile("s_waitcnt vmcnt(" #n ")" ::: "memory"); \
                      __builtin_amdgcn_sched_barrier(0); } while (0)

// ---------------- segment mean ----------------
__global__ void seg_scatter(const int* __restrict__ ids, const float* __restrict__ hidden,
                            float* __restrict__ sums, float* __restrict__ counts)
{
  int r = blockIdx.x;
  int id = ids[r];
  const float* h = hidden + (long)r * DD;
  float* s = sums + (long)id * DD;
  for (int d = threadIdx.x; d < DD; d += 256)
    atomicAdd(&s[d], h[d]);
  if (threadIdx.x == 0) atomicAdd(&counts[id], 1.0f);
}

// vectorized: float4 in, shortx4 out (192 active lanes per 768-wide row)
__global__ void build_x(const int* __restrict__ ids, const float* __restrict__ hidden,
                        const float* __restrict__ sums, const float* __restrict__ counts,
                        unsigned short* __restrict__ x)
{
  int r = blockIdx.x;
  int id = ids[r];
  float inv = 1.0f / fmaxf(counts[id], 1.0f);
  const int t = threadIdx.x;
  if (t >= 192) return;
  const floatx4* h = (const floatx4*)(hidden + (long)r * DD);
  const floatx4* s = (const floatx4*)(sums + (long)id * DD);
  unsigned short* xr = x + (long)r * IN2;
  floatx4 hv = h[t], sv = s[t];
  shortx4 a, bq;
  #pragma unroll
  for (int e = 0; e < 4; e++) {
    a[e]  = (short)f2bf(hv[e]);
    bq[e] = (short)f2bf(sv[e] * inv);
  }
  *(shortx4*)(xr + t * 4) = a;
  *(shortx4*)(xr + DD + t * 4) = bq;
}

// -------- weight conversion with gate-interleave permutation: row' = u*4+g <- row g*768+u --------
__global__ void conv_w_perm(const float* __restrict__ w, unsigned short* __restrict__ o, int K)
{
  long i = (long)blockIdx.x * 256 + threadIdx.x;
  if (i >= (long)G4 * K) return;
  int row = (int)(i / K); int k = (int)(i - (long)row * K);
  int u = row >> 2, g = row & 3;
  o[i] = f2bf(w[((long)(g * DD + u)) * K + k]);
}

__global__ void conv_bias_perm(const float* __restrict__ bif, const float* __restrict__ bhf,
                               const float* __restrict__ bib, const float* __restrict__ bhb,
                               float* __restrict__ o)
{
  int n = blockIdx.x * 256 + threadIdx.x;
  if (n >= NB2) return;
  int d = n / G4, rr = n - d * G4, u = rr >> 2, g = rr & 3;
  int s = g * DD + u;
  o[n] = d ? (bib[s] + bhb[s]) : (bif[s] + bhf[s]);
}

// ---------------- 256x256-tile GEMM (proven R6): phase-interleaved counted-vmcnt ----------------
__global__ __launch_bounds__(512, 1)
void gemm_bt256(const unsigned short* __restrict__ A, int lda,
                const unsigned short* __restrict__ B, int ldb,
                unsigned short* __restrict__ C, int ldc,
                const float* __restrict__ bias, int K)
{
  __shared__ unsigned short lA[2][16384];
  __shared__ unsigned short lB[2][16384];
  const int t = threadIdx.x;
  const int lane = t & 63;
  const int wv = t >> 6;
  const int wm = wv >> 1;
  const int wn = wv & 1;
  const int l15 = lane & 15, q = lane >> 4;
  const long m0 = (long)blockIdx.x * 256;
  const long n0 = (long)blockIdx.y * 256;
  const int rs  = t >> 2;
  const int sc  = (((t & 3) ^ ((t >> 3) & 3))) * 8;
  const int qsw = (q ^ ((l15 >> 1) & 3)) * 8;

  const unsigned short* gA = A + (m0 + rs) * (long)lda + sc;
  const unsigned short* gB = B + (n0 + rs) * (long)ldb + sc;
  const long a128 = (long)128 * lda;
  const long b128 = (long)128 * ldb;

  #define PIECE(b, kt, p, hf) do {                                               \
    const long kb_ = (long)(kt) * 64 + (p) * 32;                                 \
    gl_lds16(gA + kb_ + (hf) * a128, &lA[b][(p) * 8192 + (hf) * 4096 + t * 8]);  \
    gl_lds16(gB + kb_ + (hf) * b128, &lB[b][(p) * 8192 + (hf) * 4096 + t * 8]);  \
  } while (0)

  floatx4 acc[4][8];
  #pragma unroll
  for (int i = 0; i < 4; i++)
    #pragma unroll
    for (int j = 0; j < 8; j++)
      acc[i][j] = (floatx4){0.f, 0.f, 0.f, 0.f};

  PIECE(0, 0, 0, 0); PIECE(0, 0, 0, 1);
  PIECE(0, 0, 1, 0); PIECE(0, 0, 1, 1);

  #pragma unroll 2
  for (int kt = 0; kt < 24; kt++) {
    const int cur = kt & 1;
    const int nxt = cur ^ 1;
    const unsigned short* pA = &lA[cur][0];
    const unsigned short* pB = &lB[cur][0];

    VMCNT(4);
    __builtin_amdgcn_s_barrier();

    #pragma unroll
    for (int ks = 0; ks < 2; ks++) {
      short8 bfr[8];
      #pragma unroll
      for (int ih = 0; ih < 2; ih++) {
        if (kt < 23) {
          if (ks == 0 && ih == 0) PIECE(nxt, kt + 1, 0, 0);
          if (ks == 0 && ih == 1) PIECE(nxt, kt + 1, 0, 1);
          if (ks == 1 && ih == 0) PIECE(nxt, kt + 1, 1, 0);
          if (ks == 1 && ih == 1) PIECE(nxt, kt + 1, 1, 1);
        }
        if (ih == 0) {
          #pragma unroll
          for (int j = 0; j < 8; j++)
            bfr[j] = *(const short8*)(pB + ks * 8192 + (wn * 128 + j * 16 + l15) * 32 + qsw);
        }
        short8 af[2];
        #pragma unroll
        for (int ii = 0; ii < 2; ii++)
          af[ii] = *(const short8*)(pA + ks * 8192 + (wm * 64 + (ih * 2 + ii) * 16 + l15) * 32 + qsw);
        __builtin_amdgcn_s_setprio(1);
        #pragma unroll
        for (int ii = 0; ii < 2; ii++)
          #pragma unroll
          for (int j = 0; j < 8; j++)
            acc[ih * 2 + ii][j] =
              __builtin_amdgcn_mfma_f32_16x16x32_bf16(af[ii], bfr[j], acc[ih * 2 + ii][j], 0, 0, 0);
        __builtin_amdgcn_s_setprio(0);
      }
      if (ks == 0) {
        if (kt < 23) VMCNT(4); else VMCNT(0);
        __builtin_amdgcn_s_barrier();
      }
    }
  }
  #undef PIECE

  #pragma unroll
  for (int i = 0; i < 4; i++) {
    #pragma unroll
    for (int j = 0; j < 8; j++) {
      const long mg = m0 + wm * 64 + i * 16 + q * 4;
      const long ng = n0 + wn * 128 + j * 16 + l15;
      const float bb = bias[ng];
      #pragma unroll
      for (int r = 0; r < 4; r++)
        C[(mg + r) * (long)ldc + ng] = f2bf(acc[i][j][r] + bb);
    }
  }
}

// ---------------- persistent bidirectional LSTM recurrence (R9-proven, verbatim) ----------------
// XCD-local h (group = bid&7 -> one XCD). K=64 tiles (12/step), triple-buffered,
// prefetch distance 2, counted vmcnt (never 0 mid-loop). whh tiles 0,1 of step s+1
// prefetched before the group barrier. NT xg loads / outc stores.
// vmcnt ledger: step top outstanding Bpre(4) xg(8) A0(2) A1(2);
// j=0: VMCNT(2)  j=1..10: VMCNT(4)  j=11: VMCNT(0)
template<int LOCAL>
__global__ __launch_bounds__(512, 1)
void lstm_persist(const unsigned short* __restrict__ xg, int ldxg,
                  const unsigned short* __restrict__ whh,   // [2][3072][768] permuted
                  unsigned short* __restrict__ hbuf,        // [2][ndir][512][768]
                  unsigned short* __restrict__ outc,        // [16384][1536]
                  unsigned* bar,                            // 8 groups x 16 u32
                  int dir0, int ndir)
{
  __shared__ unsigned short bufA[3][8192];    // 3 tiles x 2 panels [128][32], swizzled
  __shared__ unsigned short bufB[3][8192];
  __shared__ unsigned short hout[128 * 40];   // h staging, pad 40

  const int bid = blockIdx.x;
  int dm, nt;
  if (LOCAL) { dm = bid & 7; nt = bid >> 3; }            // group per XCD
  else { int xcd = bid & 7; int idx = bid >> 3;
         dm = idx & 3; nt = (idx >> 2) * 8 + xcd; }
  const int ld  = (ndir == 2) ? (dm & 1) : 0;
  const int dir = dir0 + ld;
  const int mt  = (ndir == 2) ? (dm >> 1) : dm;
  const int m0 = mt * 128, n0 = nt * 128;
  const int u0 = n0 >> 2;
  unsigned* gbar = bar + dm * 16;
  const int nb24 = 24;

  const int t0 = threadIdx.x;
  const int lane = t0 & 63;
  const int wv = t0 >> 6;            // 0..7
  const int wm = wv >> 1;            // 0..3 : 32-row band
  const int wn = wv & 1;             // 0..1 : 64-col half
  const int l15 = lane & 15, q = lane >> 4;
  const long ldoff = (ndir == 2 && ld == 1) ? (long)G4 : 0;

  const unsigned short* Bdir = whh + (long)dir * G4 * DD;
  const int srow  = lane >> 2;                               // 0..15
  const int scolA = (((lane & 3) ^ ((lane >> 3) & 3))) * 8;  // staging source slot
  const int qsw   = (q ^ ((l15 >> 1) & 3)) * 8;              // fragment read slot

  const int rb = wv * 16 + srow;                             // staged row 0..127
  const unsigned short* wB  = Bdir + (long)(n0 + rb) * DD + scolA;
  const unsigned short* hA0 = hbuf + ((long)0 * ndir + ld) * ((long)SS * DD) + (long)(m0 + rb) * DD + scolA;
  const unsigned short* hA1 = hbuf + ((long)1 * ndir + ld) * ((long)SS * DD) + (long)(m0 + rb) * DD + scolA;

  // per-wave staging: 2 instr per matrix per K=64 tile (2 panels of [128][32])
  #define STAGE_B(j, b) do { const long kb_ = (long)(j) * 64;                 \
    gl_lds16(wB + kb_,      &bufB[b][wv * 512 + lane * 8]);                   \
    gl_lds16(wB + kb_ + 32, &bufB[b][4096 + wv * 512 + lane * 8]); } while (0)
  #define STAGE_A(j, b) do { const long kb_ = (long)(j) * 64;                 \
    gl_lds16_h<LOCAL>(hA + kb_,      &bufA[b][wv * 512 + lane * 8]);          \
    gl_lds16_h<LOCAL>(hA + kb_ + 32, &bufA[b][4096 + wv * 512 + lane * 8]); } while (0)

  float c_reg[2][4];
  #pragma unroll
  for (int i = 0; i < 2; i++)
    #pragma unroll
    for (int j = 0; j < 4; j++)
      c_reg[i][j] = 0.f;

  for (int s = 0; s < BB; s++) {
    const int tt = dir ? (BB - 1 - s) : s;
    const unsigned short* hA = (s & 1) ? hA1 : hA0;
    unsigned short* hw = hbuf + (((long)((s + 1) & 1)) * ndir + ld) * ((long)SS * DD);

    // ---- step prologue. Steady state: B tiles 0,1 already prefetched pre-barrier.
    if (s == 0) { STAGE_B(0, 0); STAGE_B(1, 1); }
    shortx4 xr0[4], xr1[4];
    {
      const unsigned short* xb = xg + ((long)tt * SS + m0) * ldxg + ldoff + n0;
      const unsigned short* xb0 = xb + (long)(wm * 32 + l15) * ldxg + wn * 64 + q * 4;
      const unsigned short* xb1 = xb0 + (long)16 * ldxg;
      #pragma unroll
      for (int jj = 0; jj < 4; jj++) {
        xr0[jj] = __builtin_nontemporal_load((const shortx4*)(xb0 + jj * 16));
        xr1[jj] = __builtin_nontemporal_load((const shortx4*)(xb1 + jj * 16));
      }
    }
    STAGE_A(0, 0);
    STAGE_A(1, 1);

    floatx4 acc[2][4];
    #pragma unroll
    for (int i = 0; i < 2; i++)
      #pragma unroll
      for (int j = 0; j < 4; j++)
        acc[i][j] = (floatx4){0.f, 0.f, 0.f, 0.f};

    // ---- 12 K=64 tiles, triple-buffered, distance-2, counted vmcnt ----
    #pragma unroll
    for (int j12 = 0; j12 < 12; j12++) {
      if (j12 == 0)       VMCNT(2);   // tile0 (Bpre+A0) landed; A1 in flight
      else if (j12 < 11)  VMCNT(4);   // tile j landed; stage(j+1) in flight
      else                VMCNT(0);   // tile11 landed
      __builtin_amdgcn_s_barrier();
      if (j12 < 10) {                 // stage tile j+2 (overwrites buf read in j-1: safe)
        const int bn = (j12 + 2) % 3;
        STAGE_B(j12 + 2, bn);         // B first: longest latency
        STAGE_A(j12 + 2, bn);
      }
      const int b = j12 % 3;
      __builtin_amdgcn_s_setprio(1);
      #pragma unroll
      for (int ks = 0; ks < 2; ks++) {
        const unsigned short* pA = &bufA[b][ks * 4096];
        const unsigned short* pB = &bufB[b][ks * 4096];
        short8 af[2], bfr[4];
        #pragma unroll
        for (int i = 0; i < 2; i++)
          af[i] = *(const short8*)(pA + (wm * 32 + i * 16 + l15) * 32 + qsw);
        #pragma unroll
        for (int j = 0; j < 4; j++)
          bfr[j] = *(const short8*)(pB + (wn * 64 + j * 16 + l15) * 32 + qsw);
        #pragma unroll
        for (int i = 0; i < 2; i++)
          #pragma unroll
          for (int j = 0; j < 4; j++)
            acc[i][j] = __builtin_amdgcn_mfma_f32_16x16x32_bf16(bfr[j], af[i], acc[i][j], 0, 0, 0);
      }
      __builtin_amdgcn_s_setprio(0);
    }

    // ---- zero-shuffle gate epilogue (xg from registers) ----
    #pragma unroll
    for (int i = 0; i < 2; i++) {
      const int mrow = wm * 32 + i * 16 + l15;
      #pragma unroll
      for (int j = 0; j < 4; j++) {
        const int nb = wn * 64 + j * 16 + q * 4;
        shortx4 xv = i ? xr1[j] : xr0[j];
        float gi = acc[i][j][0] + bf2f((unsigned short)xv[0]);
        float gf = acc[i][j][1] + bf2f((unsigned short)xv[1]);
        float gg = acc[i][j][2] + bf2f((unsigned short)xv[2]);
        float go = acc[i][j][3] + bf2f((unsigned short)xv[3]);
        float c = sigf(gf) * c_reg[i][j] + sigf(gi) * tanhfast(gg);
        float h = sigf(go) * tanhfast(c);
        c_reg[i][j] = c;
        hout[mrow * 40 + (nb >> 2)] = f2bf(h);
      }
    }
    __syncthreads();
    {
      const int row = t0 >> 2;
      const int qq = t0 & 3;
      short8 v0 = *(const short8*)(hout + row * 40 + qq * 8);
      unsigned short* hwp = hw + (long)(m0 + row) * DD + u0 + qq * 8;
      unsigned short* op  = outc + ((long)tt * SS + m0 + row) * IN2 + dir * DD + u0 + qq * 8;
      if (LOCAL) *(short8*)hwp = v0;     // same-XCD consumers: L2 is the coherence point
      else       store16_sc1(hwp, v0);   // cross-XCD consumers: through L3
      __builtin_nontemporal_store(v0, (short8*)op);
    }
    if (s < BB - 1) {
      VMCNT(0);                          // only the 2 epilogue stores outstanding
      __builtin_amdgcn_s_barrier();      // all waves' stores drained
      STAGE_B(0, 0);                     // prefetch next step's whh tiles across the barrier
      STAGE_B(1, 1);                     // (static data; hides L3 latency at pipeline fill)
      if (threadIdx.x == 0) {
        unsigned g = __hip_atomic_load(gbar + 1, __ATOMIC_RELAXED, __HIP_MEMORY_SCOPE_AGENT);
        unsigned a = __hip_atomic_fetch_add(gbar, 1u, __ATOMIC_RELAXED, __HIP_MEMORY_SCOPE_AGENT);
        if (a == (unsigned)(nb24 - 1)) {
          __hip_atomic_store(gbar, 0u, __ATOMIC_RELAXED, __HIP_MEMORY_SCOPE_AGENT);
          __hip_atomic_store(gbar + 1, g + 1u, __ATOMIC_RELEASE, __HIP_MEMORY_SCOPE_AGENT);
        } else {
          unsigned curv;
          do {
            __builtin_amdgcn_s_sleep(2);
            curv = __hip_atomic_load(gbar + 1, __ATOMIC_RELAXED, __HIP_MEMORY_SCOPE_AGENT);
          } while (curv == g);
        }
      }
      __builtin_amdgcn_s_barrier();
    }
  }
  #undef STAGE_A
  #undef STAGE_B
}

// ---------------- final linear [16384,1536](bf16) x [9,1536]^T ----------------
// 2 rows/block; w held in registers (reused across rows); short8 x-loads.
__global__ void final_linear(const unsigned short* __restrict__ xin, const float* __restrict__ w,
                             const float* __restrict__ b, float* __restrict__ out)
{
  __shared__ float red[NCLS * 256];
  const int t = threadIdx.x;
  const bool act = t < 192;             // 192 * 8 = 1536
  float wr[NCLS][8];
  if (act) {
    #pragma unroll
    for (int c = 0; c < NCLS; c++) {
      floatx4 w0 = *(const floatx4*)(w + c * IN2 + t * 8);
      floatx4 w1 = *(const floatx4*)(w + c * IN2 + t * 8 + 4);
      #pragma unroll
      for (int e = 0; e < 4; e++) { wr[c][e] = w0[e]; wr[c][4 + e] = w1[e]; }
    }
  }
  #pragma unroll
  for (int rr = 0; rr < 2; rr++) {
    const long row = (long)blockIdx.x * 2 + rr;
    float p[NCLS];
    #pragma unroll
    for (int c = 0; c < NCLS; c++) p[c] = 0.f;
    if (act) {
      short8 v = *(const short8*)(xin + row * IN2 + t * 8);
      float xf[8];
      #pragma unroll
      for (int e = 0; e < 8; e++) xf[e] = bf2f((unsigned short)v[e]);
      #pragma unroll
      for (int c = 0; c < NCLS; c++) {
        float s = 0.f;
        #pragma unroll
        for (int e = 0; e < 8; e++) s += xf[e] * wr[c][e];
        p[c] = s;
      }
    }
    if (rr) __syncthreads();            // red reuse across rows
    #pragma unroll
    for (int c = 0; c < NCLS; c++) red[c * 256 + t] = p[c];
    __syncthreads();
    for (int s = 128; s > 0; s >>= 1) {
      if (t < s) {
        #pragma unroll
        for (int c = 0; c < NCLS; c++)
          red[c * 256 + t] += red[c * 256 + t + s];
      }
      __syncthreads();
    }
    if (t < NCLS)
      out[row * NCLS + t] = red[t * 256] + b[t];
  }
}

extern "C" void kernel_launch(void* const* d_in, const int* in_sizes, int n_in,
                              void* d_out, int out_size, void* d_ws, size_t ws_size,
                              hipStream_t stream)
{
  const int*   batch  = (const int*)d_in[0];
  const float* hidden = (const float*)d_in[1];
  const float* w_ih_f = (const float*)d_in[2];
  const float* w_hh_f = (const float*)d_in[3];
  const float* b_ih_f = (const float*)d_in[4];
  const float* b_hh_f = (const float*)d_in[5];
  const float* w_ih_b = (const float*)d_in[6];
  const float* w_hh_b = (const float*)d_in[7];
  const float* b_ih_b = (const float*)d_in[8];
  const float* b_hh_b = (const float*)d_in[9];
  const float* lin_w  = (const float*)d_in[10];
  const float* lin_b  = (const float*)d_in[11];
  float* out = (float*)d_out;

  char* ws = (char*)d_ws;
  size_t off = 0;
  auto alloc = [&](size_t bytes) -> char* {
    char* p = ws + off;
    off += (bytes + 255) & ~(size_t)255;
    return p;
  };

  const size_t SZ_XG_A = (size_t)ROWS * NB2 * 2;      // 201.3 MB
  const size_t SZ_XG_B = (size_t)ROWS * G4  * 2;      // 100.7 MB
  const size_t SZ_XBF  = (size_t)ROWS * IN2 * 2;      //  50.3 MB
  const size_t SZ_W    = (size_t)G4 * IN2 * 2;        //   9.4 MB
  const size_t SZ_BIAS = (size_t)NB2 * 4;
  const size_t SZ_HBUF = (size_t)2 * 2 * SS * DD * 2; //   3.1 MB
  const size_t SZ_BAR  = 512;
  const size_t SZ_SUMS = (size_t)VOCAB * DD * 4 + (size_t)VOCAB * 4;

  const size_t NEED_C = SZ_XG_A + SZ_XBF + SZ_W + SZ_BIAS + SZ_HBUF + SZ_BAR + 8 * 256;
  const bool combined = ws_size >= NEED_C;

  const long nWIH = (long)G4 * IN2;
  const long nWHH = (long)G4 * DD;

  if (combined) {
    unsigned short* xg   = (unsigned short*)alloc(SZ_XG_A);
    unsigned short* xbf  = (unsigned short*)alloc(SZ_XBF);   // x input, later reused as outc
    unsigned short* wbuf = (unsigned short*)alloc(SZ_W);     // wih_f -> wih_b -> whh(both)
    float*          bias = (float*)alloc(SZ_BIAS);
    unsigned short* hbuf = (unsigned short*)alloc(SZ_HBUF);
    unsigned*       bar  = (unsigned*)alloc(SZ_BAR);
    float* sums   = (float*)xg;                              // overlay, consumed pre-xg-GEMM
    float* counts = sums + (size_t)VOCAB * DD;

    hipMemsetAsync(sums, 0, SZ_SUMS, stream);
    hipMemsetAsync(bar, 0, SZ_BAR, stream);
    seg_scatter<<<ROWS, 256, 0, stream>>>(batch, hidden, sums, counts);
    build_x<<<ROWS, 256, 0, stream>>>(batch, hidden, sums, counts, xbf);
    conv_bias_perm<<<(NB2 + 255) / 256, 256, 0, stream>>>(b_ih_f, b_hh_f, b_ih_b, b_hh_b, bias);

    for (int dir = 0; dir < 2; dir++) {
      conv_w_perm<<<(unsigned)((nWIH + 255) / 256), 256, 0, stream>>>(dir ? w_ih_b : w_ih_f, wbuf, IN2);
      dim3 grid(ROWS / 256, G4 / 256, 1);
      gemm_bt256<<<grid, 512, 0, stream>>>(xbf, IN2, wbuf, IN2,
                                           xg + (size_t)dir * G4, NB2,
                                           bias + (size_t)dir * G4, IN2);
    }
    conv_w_perm<<<(unsigned)((nWHH + 255) / 256), 256, 0, stream>>>(w_hh_f, wbuf, DD);
    conv_w_perm<<<(unsigned)((nWHH + 255) / 256), 256, 0, stream>>>(w_hh_b, wbuf + (size_t)G4 * DD, DD);

    hipMemsetAsync(hbuf, 0, SZ_HBUF, stream);
    lstm_persist<1><<<192, 512, 0, stream>>>(xg, NB2, wbuf, hbuf, xbf, bar, 0, 2);
    final_linear<<<ROWS / 2, 256, 0, stream>>>(xbf, lin_w, lin_b, out);
  } else {
    // direction-sequential (~223 MB, proven to fit)
    unsigned short* xg   = (unsigned short*)alloc(SZ_XG_B);
    unsigned short* xbf  = (unsigned short*)alloc(SZ_XBF);
    unsigned short* outc = (unsigned short*)alloc(SZ_XBF);
    unsigned short* wih  = (unsigned short*)alloc(SZ_W);
    unsigned short* whh  = (unsigned short*)alloc(SZ_W);
    float*          bias = (float*)alloc(SZ_BIAS);
    unsigned short* hbuf = (unsigned short*)alloc(SZ_HBUF);
    unsigned*       bar  = (unsigned*)alloc(SZ_BAR);
    float* sums   = (float*)xg;
    float* counts = sums + (size_t)VOCAB * DD;

    hipMemsetAsync(sums, 0, SZ_SUMS, stream);
    hipMemsetAsync(bar, 0, SZ_BAR, stream);
    seg_scatter<<<ROWS, 256, 0, stream>>>(batch, hidden, sums, counts);
    build_x<<<ROWS, 256, 0, stream>>>(batch, hidden, sums, counts, xbf);
    conv_bias_perm<<<(NB2 + 255) / 256, 256, 0, stream>>>(b_ih_f, b_hh_f, b_ih_b, b_hh_b, bias);
    conv_w_perm<<<(unsigned)((nWHH + 255) / 256), 256, 0, stream>>>(w_hh_f, whh, DD);
    conv_w_perm<<<(unsigned)((nWHH + 255) / 256), 256, 0, stream>>>(w_hh_b, whh + (size_t)G4 * DD, DD);

    for (int dir = 0; dir < 2; dir++) {
      conv_w_perm<<<(unsigned)((nWIH + 255) / 256), 256, 0, stream>>>(dir ? w_ih_b : w_ih_f, wih, IN2);
      {
        dim3 grid(ROWS / 256, G4 / 256, 1);
        gemm_bt256<<<grid, 512, 0, stream>>>(xbf, IN2, wih, IN2, xg, G4,
                                             bias + (size_t)dir * G4, IN2);
      }
      hipMemsetAsync(hbuf, 0, SZ_HBUF, stream);
      lstm_persist<0><<<96, 512, 0, stream>>>(xg, G4, whh, hbuf, outc, bar, dir, 1);
    }
    final_linear<<<ROWS / 2, 256, 0, stream>>>(outc, lin_w, lin_b, out);
  }
}

// Round 12
// 1093.828 us; speedup vs baseline: 1.1289x; 1.0041x over previous
//
#include <hip/hip_runtime.h>

#define VOCAB 28996
#define BB 32
#define SS 512
#define DD 768
#define NCLS 9
#define ROWS (BB*SS)     // 16384
#define IN2 (2*DD)       // 1536
#define G4 (4*DD)        // 3072
#define NB2 (2*G4)       // 6144

typedef __attribute__((ext_vector_type(8))) short short8;
typedef __attribute__((ext_vector_type(4))) short shortx4;
typedef __attribute__((ext_vector_type(4))) float floatx4;
typedef unsigned long long ull;

__device__ __forceinline__ float bf2f(unsigned short u){
  union { unsigned int i; float f; } v; v.i = ((unsigned int)u) << 16; return v.f;
}
__device__ __forceinline__ unsigned short f2bf(float f){
  union { float f; unsigned int i; } v; v.f = f;
  unsigned int r = v.i + 0x7FFFu + ((v.i >> 16) & 1u);
  return (unsigned short)(r >> 16);
}
__device__ __forceinline__ float sigf(float x){ return 1.0f / (1.0f + __expf(-x)); }
__device__ __forceinline__ float tanhfast(float x){
  float y = fminf(fmaxf(x, -15.f), 15.f);
  float e = __expf(2.f * y);
  return 1.f - 2.f / (e + 1.f);
}

__device__ __forceinline__ void gl_lds16(const unsigned short* g, unsigned short* l){
  __builtin_amdgcn_global_load_lds((__attribute__((address_space(1))) void*)(g),
                                   (__attribute__((address_space(3))) void*)(l), 16, 0, 0);
}
// h-path load, parameterized coherence:
// LOCAL=1: sc0 only -> bypass L1, read the block's own XCD L2 (producers same-XCD)
// LOCAL=0: sc0|sc1  -> bypass L1+L2, read memory-side L3 (producers cross-XCD)
template<int LOCAL>
__device__ __forceinline__ void gl_lds16_h(const unsigned short* g, unsigned short* l){
  __builtin_amdgcn_global_load_lds((__attribute__((address_space(1))) void*)(g),
                                   (__attribute__((address_space(3))) void*)(l), 16, 0,
                                   LOCAL ? 1 : 17);
}
// write-through store to the coherence point (L3) so sc1 readers on other XCDs see it
__device__ __forceinline__ void store16_sc1(unsigned short* p, short8 v){
  asm volatile("global_store_dwordx4 %0, %1, off sc0 sc1" :: "v"(p), "v"(v) : "memory");
}

#define VMCNT(n) do { asm volatile("s_waitcnt vmcnt(" #n ")" ::: "memory"); \
                      __builtin_amdgcn_sched_barrier(0); } while (0)

// ---------------- segment mean ----------------
__global__ void seg_scatter(const int* __restrict__ ids, const float* __restrict__ hidden,
                            float* __restrict__ sums, float* __restrict__ counts)
{
  int r = blockIdx.x;
  int id = ids[r];
  const float* h = hidden + (long)r * DD;
  float* s = sums + (long)id * DD;
  for (int d = threadIdx.x; d < DD; d += 256)
    atomicAdd(&s[d], h[d]);
  if (threadIdx.x == 0) atomicAdd(&counts[id], 1.0f);
}

// vectorized: float4 in, shortx4 out (192 active lanes per 768-wide row)
__global__ void build_x(const int* __restrict__ ids, const float* __restrict__ hidden,
                        const float* __restrict__ sums, const float* __restrict__ counts,
                        unsigned short* __restrict__ x)
{
  int r = blockIdx.x;
  int id = ids[r];
  float inv = 1.0f / fmaxf(counts[id], 1.0f);
  const int t = threadIdx.x;
  if (t >= 192) return;
  const floatx4* h = (const floatx4*)(hidden + (long)r * DD);
  const floatx4* s = (const floatx4*)(sums + (long)id * DD);
  unsigned short* xr = x + (long)r * IN2;
  floatx4 hv = h[t], sv = s[t];
  shortx4 a, bq;
  #pragma unroll
  for (int e = 0; e < 4; e++) {
    a[e]  = (short)f2bf(hv[e]);
    bq[e] = (short)f2bf(sv[e] * inv);
  }
  *(shortx4*)(xr + t * 4) = a;
  *(shortx4*)(xr + DD + t * 4) = bq;
}

// -------- weight conversion with gate-interleave permutation: row' = u*4+g <- row g*768+u --------
__global__ void conv_w_perm(const float* __restrict__ w, unsigned short* __restrict__ o, int K)
{
  long i = (long)blockIdx.x * 256 + threadIdx.x;
  if (i >= (long)G4 * K) return;
  int row = (int)(i / K); int k = (int)(i - (long)row * K);
  int u = row >> 2, g = row & 3;
  o[i] = f2bf(w[((long)(g * DD + u)) * K + k]);
}

__global__ void conv_bias_perm(const float* __restrict__ bif, const float* __restrict__ bhf,
                               const float* __restrict__ bib, const float* __restrict__ bhb,
                               float* __restrict__ o)
{
  int n = blockIdx.x * 256 + threadIdx.x;
  if (n >= NB2) return;
  int d = n / G4, rr = n - d * G4, u = rr >> 2, g = rr & 3;
  int s = g * DD + u;
  o[n] = d ? (bib[s] + bhb[s]) : (bif[s] + bhf[s]);
}

// ---------------- 256x256-tile GEMM: 4-phase counted-vmcnt schedule ----------------
// 512 threads / 8 waves (4M x 2N, wave tile 64x128). K-tile 64, double-buffered.
// LDS layout per buf: [half h (128 rows)][panel p (32 cols)][128 rows][32 shorts swz].
// Per K-tile: 4 phases, each = {2 stage-loads for tile kt+1 -> 4-8 ds_read_b128 ->
// setprio(1) -> 16 MFMA -> setprio(0)}. Exactly 2 checkpoints per tile, both
// VMCNT(4)+barrier (never 0 mid-loop; last tile peeled):
//   tile-top: outstanding kt.p0(4)+kt.p1(4) -> VMCNT(4) lands p0 (panels ks=0)
//   mid-tile: outstanding kt.p1(4)+(kt+1).p0(4) -> VMCNT(4) lands p1 (panels ks=1)
__global__ __launch_bounds__(512, 1)
void gemm_bt256(const unsigned short* __restrict__ A, int lda,
                const unsigned short* __restrict__ B, int ldb,
                unsigned short* __restrict__ C, int ldc,
                const float* __restrict__ bias, int K)
{
  __shared__ unsigned short lA[2][16384];
  __shared__ unsigned short lB[2][16384];
  const int t = threadIdx.x;
  const int lane = t & 63;
  const int wv = t >> 6;
  const int wm = wv >> 1;        // 0..3 : 64-row band
  const int wn = wv & 1;         // 0..1 : 128-col half
  const int l15 = lane & 15, q = lane >> 4;
  const long m0 = (long)blockIdx.x * 256;
  const long n0 = (long)blockIdx.y * 256;
  const int rs  = t >> 2;
  const int sc  = (((t & 3) ^ ((t >> 3) & 3))) * 8;   // swizzled staging source slot
  const int qsw = (q ^ ((l15 >> 1) & 3)) * 8;         // swizzled fragment read slot

  const unsigned short* gA = A + (m0 + rs) * (long)lda + sc;
  const unsigned short* gB = B + (n0 + rs) * (long)ldb + sc;
  const long a128 = (long)128 * lda;
  const long b128 = (long)128 * ldb;

  // one piece = [128 rows (half h_)][32 cols (panel p_)] of one matrix, 1 instr/wave
  #define PA(bf_, kt_, h_, p_) gl_lds16(gA + (long)(kt_) * 64 + (h_) * a128 + (p_) * 32, \
                                        &lA[bf_][(h_) * 8192 + (p_) * 4096 + t * 8])
  #define PB(bf_, kt_, h_, p_) gl_lds16(gB + (long)(kt_) * 64 + (h_) * b128 + (p_) * 32, \
                                        &lB[bf_][(h_) * 8192 + (p_) * 4096 + t * 8])

  const int baseA = (wm >> 1) * 8192 + ((wm & 1) * 64 + l15) * 32 + qsw;
  const int baseB = wn * 8192 + l15 * 32 + qsw;

  floatx4 acc[4][8];
  #pragma unroll
  for (int i = 0; i < 4; i++)
    #pragma unroll
    for (int j = 0; j < 8; j++)
      acc[i][j] = (floatx4){0.f, 0.f, 0.f, 0.f};

  // prologue: tile 0 fully -- p0 pieces first, then p1 (order = vmcnt ledger order)
  PA(0, 0, 0, 0); PA(0, 0, 1, 0); PB(0, 0, 0, 0); PB(0, 0, 1, 0);
  PA(0, 0, 0, 1); PA(0, 0, 1, 1); PB(0, 0, 0, 1); PB(0, 0, 1, 1);

  #pragma unroll 2
  for (int kt = 0; kt < 23; kt++) {
    const int b = kt & 1, nb = b ^ 1;
    const unsigned short* pAb = &lA[b][0];
    const unsigned short* pBb = &lB[b][0];
    #pragma unroll
    for (int ks = 0; ks < 2; ks++) {
      VMCNT(4);                          // panels ks of tile kt landed (per-wave)
      __builtin_amdgcn_s_barrier();      // ...for all waves
      // phase 1: stage next-tile A panel ks; read af + bf[0..3]; 16 MFMA
      PA(nb, kt + 1, 0, ks); PA(nb, kt + 1, 1, ks);
      short8 af[4], bf[4];
      #pragma unroll
      for (int i = 0; i < 4; i++)
        af[i] = *(const short8*)(pAb + baseA + ks * 4096 + i * 512);
      #pragma unroll
      for (int j = 0; j < 4; j++)
        bf[j] = *(const short8*)(pBb + baseB + ks * 4096 + j * 512);
      __builtin_amdgcn_s_setprio(1);
      #pragma unroll
      for (int i = 0; i < 4; i++)
        #pragma unroll
        for (int j = 0; j < 4; j++)
          acc[i][j] = __builtin_amdgcn_mfma_f32_16x16x32_bf16(af[i], bf[j], acc[i][j], 0, 0, 0);
      __builtin_amdgcn_s_setprio(0);
      // phase 2: stage next-tile B panel ks; read bf[4..7]; 16 MFMA
      PB(nb, kt + 1, 0, ks); PB(nb, kt + 1, 1, ks);
      #pragma unroll
      for (int j = 0; j < 4; j++)
        bf[j] = *(const short8*)(pBb + baseB + ks * 4096 + (4 + j) * 512);
      __builtin_amdgcn_s_setprio(1);
      #pragma unroll
      for (int i = 0; i < 4; i++)
        #pragma unroll
        for (int j = 0; j < 4; j++)
          acc[i][4 + j] = __builtin_amdgcn_mfma_f32_16x16x32_bf16(af[i], bf[j], acc[i][4 + j], 0, 0, 0);
      __builtin_amdgcn_s_setprio(0);
    }
  }
  // tile 23 (peeled: no next-tile staging; drain to 0 only at the last checkpoint)
  {
    const unsigned short* pAb = &lA[1][0];
    const unsigned short* pBb = &lB[1][0];
    #pragma unroll
    for (int ks = 0; ks < 2; ks++) {
      if (ks == 0) { VMCNT(4); } else { VMCNT(0); }
      __builtin_amdgcn_s_barrier();
      short8 af[4], bf[4];
      #pragma unroll
      for (int i = 0; i < 4; i++)
        af[i] = *(const short8*)(pAb + baseA + ks * 4096 + i * 512);
      #pragma unroll
      for (int j = 0; j < 4; j++)
        bf[j] = *(const short8*)(pBb + baseB + ks * 4096 + j * 512);
      __builtin_amdgcn_s_setprio(1);
      #pragma unroll
      for (int i = 0; i < 4; i++)
        #pragma unroll
        for (int j = 0; j < 4; j++)
          acc[i][j] = __builtin_amdgcn_mfma_f32_16x16x32_bf16(af[i], bf[j], acc[i][j], 0, 0, 0);
      __builtin_amdgcn_s_setprio(0);
      #pragma unroll
      for (int j = 0; j < 4; j++)
        bf[j] = *(const short8*)(pBb + baseB + ks * 4096 + (4 + j) * 512);
      __builtin_amdgcn_s_setprio(1);
      #pragma unroll
      for (int i = 0; i < 4; i++)
        #pragma unroll
        for (int j = 0; j < 4; j++)
          acc[i][4 + j] = __builtin_amdgcn_mfma_f32_16x16x32_bf16(af[i], bf[j], acc[i][4 + j], 0, 0, 0);
      __builtin_amdgcn_s_setprio(0);
    }
  }
  #undef PA
  #undef PB

  #pragma unroll
  for (int i = 0; i < 4; i++) {
    #pragma unroll
    for (int j = 0; j < 8; j++) {
      const long mg = m0 + wm * 64 + i * 16 + q * 4;
      const long ng = n0 + wn * 128 + j * 16 + l15;
      const float bb = bias[ng];
      #pragma unroll
      for (int r = 0; r < 4; r++)
        C[(mg + r) * (long)ldc + ng] = f2bf(acc[i][j][r] + bb);
    }
  }
}

// ---------------- persistent bidirectional LSTM recurrence (R9-proven, verbatim) ----------------
// XCD-local h (group = bid&7 -> one XCD). K=64 tiles (12/step), triple-buffered,
// prefetch distance 2, counted vmcnt (never 0 mid-loop). whh tiles 0,1 of step s+1
// prefetched before the group barrier. NT xg loads / outc stores.
// vmcnt ledger: step top outstanding Bpre(4) xg(8) A0(2) A1(2);
// j=0: VMCNT(2)  j=1..10: VMCNT(4)  j=11: VMCNT(0)
template<int LOCAL>
__global__ __launch_bounds__(512, 1)
void lstm_persist(const unsigned short* __restrict__ xg, int ldxg,
                  const unsigned short* __restrict__ whh,   // [2][3072][768] permuted
                  unsigned short* __restrict__ hbuf,        // [2][ndir][512][768]
                  unsigned short* __restrict__ outc,        // [16384][1536]
                  unsigned* bar,                            // 8 groups x 16 u32
                  int dir0, int ndir)
{
  __shared__ unsigned short bufA[3][8192];    // 3 tiles x 2 panels [128][32], swizzled
  __shared__ unsigned short bufB[3][8192];
  __shared__ unsigned short hout[128 * 40];   // h staging, pad 40

  const int bid = blockIdx.x;
  int dm, nt;
  if (LOCAL) { dm = bid & 7; nt = bid >> 3; }            // group per XCD
  else { int xcd = bid & 7; int idx = bid >> 3;
         dm = idx & 3; nt = (idx >> 2) * 8 + xcd; }
  const int ld  = (ndir == 2) ? (dm & 1) : 0;
  const int dir = dir0 + ld;
  const int mt  = (ndir == 2) ? (dm >> 1) : dm;
  const int m0 = mt * 128, n0 = nt * 128;
  const int u0 = n0 >> 2;
  unsigned* gbar = bar + dm * 16;
  const int nb24 = 24;

  const int t0 = threadIdx.x;
  const int lane = t0 & 63;
  const int wv = t0 >> 6;            // 0..7
  const int wm = wv >> 1;            // 0..3 : 32-row band
  const int wn = wv & 1;             // 0..1 : 64-col half
  const int l15 = lane & 15, q = lane >> 4;
  const long ldoff = (ndir == 2 && ld == 1) ? (long)G4 : 0;

  const unsigned short* Bdir = whh + (long)dir * G4 * DD;
  const int srow  = lane >> 2;                               // 0..15
  const int scolA = (((lane & 3) ^ ((lane >> 3) & 3))) * 8;  // staging source slot
  const int qsw   = (q ^ ((l15 >> 1) & 3)) * 8;              // fragment read slot

  const int rb = wv * 16 + srow;                             // staged row 0..127
  const unsigned short* wB  = Bdir + (long)(n0 + rb) * DD + scolA;
  const unsigned short* hA0 = hbuf + ((long)0 * ndir + ld) * ((long)SS * DD) + (long)(m0 + rb) * DD + scolA;
  const unsigned short* hA1 = hbuf + ((long)1 * ndir + ld) * ((long)SS * DD) + (long)(m0 + rb) * DD + scolA;

  // per-wave staging: 2 instr per matrix per K=64 tile (2 panels of [128][32])
  #define STAGE_B(j, b) do { const long kb_ = (long)(j) * 64;                 \
    gl_lds16(wB + kb_,      &bufB[b][wv * 512 + lane * 8]);                   \
    gl_lds16(wB + kb_ + 32, &bufB[b][4096 + wv * 512 + lane * 8]); } while (0)
  #define STAGE_A(j, b) do { const long kb_ = (long)(j) * 64;                 \
    gl_lds16_h<LOCAL>(hA + kb_,      &bufA[b][wv * 512 + lane * 8]);          \
    gl_lds16_h<LOCAL>(hA + kb_ + 32, &bufA[b][4096 + wv * 512 + lane * 8]); } while (0)

  float c_reg[2][4];
  #pragma unroll
  for (int i = 0; i < 2; i++)
    #pragma unroll
    for (int j = 0; j < 4; j++)
      c_reg[i][j] = 0.f;

  for (int s = 0; s < BB; s++) {
    const int tt = dir ? (BB - 1 - s) : s;
    const unsigned short* hA = (s & 1) ? hA1 : hA0;
    unsigned short* hw = hbuf + (((long)((s + 1) & 1)) * ndir + ld) * ((long)SS * DD);

    // ---- step prologue. Steady state: B tiles 0,1 already prefetched pre-barrier.
    if (s == 0) { STAGE_B(0, 0); STAGE_B(1, 1); }
    shortx4 xr0[4], xr1[4];
    {
      const unsigned short* xb = xg + ((long)tt * SS + m0) * ldxg + ldoff + n0;
      const unsigned short* xb0 = xb + (long)(wm * 32 + l15) * ldxg + wn * 64 + q * 4;
      const unsigned short* xb1 = xb0 + (long)16 * ldxg;
      #pragma unroll
      for (int jj = 0; jj < 4; jj++) {
        xr0[jj] = __builtin_nontemporal_load((const shortx4*)(xb0 + jj * 16));
        xr1[jj] = __builtin_nontemporal_load((const shortx4*)(xb1 + jj * 16));
      }
    }
    STAGE_A(0, 0);
    STAGE_A(1, 1);

    floatx4 acc[2][4];
    #pragma unroll
    for (int i = 0; i < 2; i++)
      #pragma unroll
      for (int j = 0; j < 4; j++)
        acc[i][j] = (floatx4){0.f, 0.f, 0.f, 0.f};

    // ---- 12 K=64 tiles, triple-buffered, distance-2, counted vmcnt ----
    #pragma unroll
    for (int j12 = 0; j12 < 12; j12++) {
      if (j12 == 0)       VMCNT(2);   // tile0 (Bpre+A0) landed; A1 in flight
      else if (j12 < 11)  VMCNT(4);   // tile j landed; stage(j+1) in flight
      else                VMCNT(0);   // tile11 landed
      __builtin_amdgcn_s_barrier();
      if (j12 < 10) {                 // stage tile j+2 (overwrites buf read in j-1: safe)
        const int bn = (j12 + 2) % 3;
        STAGE_B(j12 + 2, bn);         // B first: longest latency
        STAGE_A(j12 + 2, bn);
      }
      const int b = j12 % 3;
      __builtin_amdgcn_s_setprio(1);
      #pragma unroll
      for (int ks = 0; ks < 2; ks++) {
        const unsigned short* pA = &bufA[b][ks * 4096];
        const unsigned short* pB = &bufB[b][ks * 4096];
        short8 af[2], bfr[4];
        #pragma unroll
        for (int i = 0; i < 2; i++)
          af[i] = *(const short8*)(pA + (wm * 32 + i * 16 + l15) * 32 + qsw);
        #pragma unroll
        for (int j = 0; j < 4; j++)
          bfr[j] = *(const short8*)(pB + (wn * 64 + j * 16 + l15) * 32 + qsw);
        #pragma unroll
        for (int i = 0; i < 2; i++)
          #pragma unroll
          for (int j = 0; j < 4; j++)
            acc[i][j] = __builtin_amdgcn_mfma_f32_16x16x32_bf16(bfr[j], af[i], acc[i][j], 0, 0, 0);
      }
      __builtin_amdgcn_s_setprio(0);
    }

    // ---- zero-shuffle gate epilogue (xg from registers) ----
    #pragma unroll
    for (int i = 0; i < 2; i++) {
      const int mrow = wm * 32 + i * 16 + l15;
      #pragma unroll
      for (int j = 0; j < 4; j++) {
        const int nb = wn * 64 + j * 16 + q * 4;
        shortx4 xv = i ? xr1[j] : xr0[j];
        float gi = acc[i][j][0] + bf2f((unsigned short)xv[0]);
        float gf = acc[i][j][1] + bf2f((unsigned short)xv[1]);
        float gg = acc[i][j][2] + bf2f((unsigned short)xv[2]);
        float go = acc[i][j][3] + bf2f((unsigned short)xv[3]);
        float c = sigf(gf) * c_reg[i][j] + sigf(gi) * tanhfast(gg);
        float h = sigf(go) * tanhfast(c);
        c_reg[i][j] = c;
        hout[mrow * 40 + (nb >> 2)] = f2bf(h);
      }
    }
    __syncthreads();
    {
      const int row = t0 >> 2;
      const int qq = t0 & 3;
      short8 v0 = *(const short8*)(hout + row * 40 + qq * 8);
      unsigned short* hwp = hw + (long)(m0 + row) * DD + u0 + qq * 8;
      unsigned short* op  = outc + ((long)tt * SS + m0 + row) * IN2 + dir * DD + u0 + qq * 8;
      if (LOCAL) *(short8*)hwp = v0;     // same-XCD consumers: L2 is the coherence point
      else       store16_sc1(hwp, v0);   // cross-XCD consumers: through L3
      __builtin_nontemporal_store(v0, (short8*)op);
    }
    if (s < BB - 1) {
      VMCNT(0);                          // only the 2 epilogue stores outstanding
      __builtin_amdgcn_s_barrier();      // all waves' stores drained
      STAGE_B(0, 0);                     // prefetch next step's whh tiles across the barrier
      STAGE_B(1, 1);                     // (static data; hides L3 latency at pipeline fill)
      if (threadIdx.x == 0) {
        unsigned g = __hip_atomic_load(gbar + 1, __ATOMIC_RELAXED, __HIP_MEMORY_SCOPE_AGENT);
        unsigned a = __hip_atomic_fetch_add(gbar, 1u, __ATOMIC_RELAXED, __HIP_MEMORY_SCOPE_AGENT);
        if (a == (unsigned)(nb24 - 1)) {
          __hip_atomic_store(gbar, 0u, __ATOMIC_RELAXED, __HIP_MEMORY_SCOPE_AGENT);
          __hip_atomic_store(gbar + 1, g + 1u, __ATOMIC_RELEASE, __HIP_MEMORY_SCOPE_AGENT);
        } else {
          unsigned curv;
          do {
            __builtin_amdgcn_s_sleep(2);
            curv = __hip_atomic_load(gbar + 1, __ATOMIC_RELAXED, __HIP_MEMORY_SCOPE_AGENT);
          } while (curv == g);
        }
      }
      __builtin_amdgcn_s_barrier();
    }
  }
  #undef STAGE_A
  #undef STAGE_B
}

// ---------------- final linear [16384,1536](bf16) x [9,1536]^T ----------------
// 2 rows/block; w held in registers (reused across rows); short8 x-loads.
__global__ void final_linear(const unsigned short* __restrict__ xin, const float* __restrict__ w,
                             const float* __restrict__ b, float* __restrict__ out)
{
  __shared__ float red[NCLS * 256];
  const int t = threadIdx.x;
  const bool act = t < 192;             // 192 * 8 = 1536
  float wr[NCLS][8];
  if (act) {
    #pragma unroll
    for (int c = 0; c < NCLS; c++) {
      floatx4 w0 = *(const floatx4*)(w + c * IN2 + t * 8);
      floatx4 w1 = *(const floatx4*)(w + c * IN2 + t * 8 + 4);
      #pragma unroll
      for (int e = 0; e < 4; e++) { wr[c][e] = w0[e]; wr[c][4 + e] = w1[e]; }
    }
  }
  #pragma unroll
  for (int rr = 0; rr < 2; rr++) {
    const long row = (long)blockIdx.x * 2 + rr;
    float p[NCLS];
    #pragma unroll
    for (int c = 0; c < NCLS; c++) p[c] = 0.f;
    if (act) {
      short8 v = *(const short8*)(xin + row * IN2 + t * 8);
      float xf[8];
      #pragma unroll
      for (int e = 0; e < 8; e++) xf[e] = bf2f((unsigned short)v[e]);
      #pragma unroll
      for (int c = 0; c < NCLS; c++) {
        float s = 0.f;
        #pragma unroll
        for (int e = 0; e < 8; e++) s += xf[e] * wr[c][e];
        p[c] = s;
      }
    }
    if (rr) __syncthreads();            // red reuse across rows
    #pragma unroll
    for (int c = 0; c < NCLS; c++) red[c * 256 + t] = p[c];
    __syncthreads();
    for (int s = 128; s > 0; s >>= 1) {
      if (t < s) {
        #pragma unroll
        for (int c = 0; c < NCLS; c++)
          red[c * 256 + t] += red[c * 256 + t + s];
      }
      __syncthreads();
    }
    if (t < NCLS)
      out[row * NCLS + t] = red[t * 256] + b[t];
  }
}

extern "C" void kernel_launch(void* const* d_in, const int* in_sizes, int n_in,
                              void* d_out, int out_size, void* d_ws, size_t ws_size,
                              hipStream_t stream)
{
  const int*   batch  = (const int*)d_in[0];
  const float* hidden = (const float*)d_in[1];
  const float* w_ih_f = (const float*)d_in[2];
  const float* w_hh_f = (const float*)d_in[3];
  const float* b_ih_f = (const float*)d_in[4];
  const float* b_hh_f = (const float*)d_in[5];
  const float* w_ih_b = (const float*)d_in[6];
  const float* w_hh_b = (const float*)d_in[7];
  const float* b_ih_b = (const float*)d_in[8];
  const float* b_hh_b = (const float*)d_in[9];
  const float* lin_w  = (const float*)d_in[10];
  const float* lin_b  = (const float*)d_in[11];
  float* out = (float*)d_out;

  char* ws = (char*)d_ws;
  size_t off = 0;
  auto alloc = [&](size_t bytes) -> char* {
    char* p = ws + off;
    off += (bytes + 255) & ~(size_t)255;
    return p;
  };

  const size_t SZ_XG_A = (size_t)ROWS * NB2 * 2;      // 201.3 MB
  const size_t SZ_XG_B = (size_t)ROWS * G4  * 2;      // 100.7 MB
  const size_t SZ_XBF  = (size_t)ROWS * IN2 * 2;      //  50.3 MB
  const size_t SZ_W    = (size_t)G4 * IN2 * 2;        //   9.4 MB
  const size_t SZ_BIAS = (size_t)NB2 * 4;
  const size_t SZ_HBUF = (size_t)2 * 2 * SS * DD * 2; //   3.1 MB
  const size_t SZ_BAR  = 512;
  const size_t SZ_SUMS = (size_t)VOCAB * DD * 4 + (size_t)VOCAB * 4;

  const size_t NEED_C = SZ_XG_A + SZ_XBF + SZ_W + SZ_BIAS + SZ_HBUF + SZ_BAR + 8 * 256;
  const bool combined = ws_size >= NEED_C;

  const long nWIH = (long)G4 * IN2;
  const long nWHH = (long)G4 * DD;

  if (combined) {
    unsigned short* xg   = (unsigned short*)alloc(SZ_XG_A);
    unsigned short* xbf  = (unsigned short*)alloc(SZ_XBF);   // x input, later reused as outc
    unsigned short* wbuf = (unsigned short*)alloc(SZ_W);     // wih_f -> wih_b -> whh(both)
    float*          bias = (float*)alloc(SZ_BIAS);
    unsigned short* hbuf = (unsigned short*)alloc(SZ_HBUF);
    unsigned*       bar  = (unsigned*)alloc(SZ_BAR);
    float* sums   = (float*)xg;                              // overlay, consumed pre-xg-GEMM
    float* counts = sums + (size_t)VOCAB * DD;

    hipMemsetAsync(sums, 0, SZ_SUMS, stream);
    hipMemsetAsync(bar, 0, SZ_BAR, stream);
    seg_scatter<<<ROWS, 256, 0, stream>>>(batch, hidden, sums, counts);
    build_x<<<ROWS, 256, 0, stream>>>(batch, hidden, sums, counts, xbf);
    conv_bias_perm<<<(NB2 + 255) / 256, 256, 0, stream>>>(b_ih_f, b_hh_f, b_ih_b, b_hh_b, bias);

    for (int dir = 0; dir < 2; dir++) {
      conv_w_perm<<<(unsigned)((nWIH + 255) / 256), 256, 0, stream>>>(dir ? w_ih_b : w_ih_f, wbuf, IN2);
      dim3 grid(ROWS / 256, G4 / 256, 1);
      gemm_bt256<<<grid, 512, 0, stream>>>(xbf, IN2, wbuf, IN2,
                                           xg + (size_t)dir * G4, NB2,
                                           bias + (size_t)dir * G4, IN2);
    }
    conv_w_perm<<<(unsigned)((nWHH + 255) / 256), 256, 0, stream>>>(w_hh_f, wbuf, DD);
    conv_w_perm<<<(unsigned)((nWHH + 255) / 256), 256, 0, stream>>>(w_hh_b, wbuf + (size_t)G4 * DD, DD);

    hipMemsetAsync(hbuf, 0, SZ_HBUF, stream);
    lstm_persist<1><<<192, 512, 0, stream>>>(xg, NB2, wbuf, hbuf, xbf, bar, 0, 2);
    final_linear<<<ROWS / 2, 256, 0, stream>>>(xbf, lin_w, lin_b, out);
  } else {
    // direction-sequential (~223 MB, proven to fit)
    unsigned short* xg   = (unsigned short*)alloc(SZ_XG_B);
    unsigned short* xbf  = (unsigned short*)alloc(SZ_XBF);
    unsigned short* outc = (unsigned short*)alloc(SZ_XBF);
    unsigned short* wih  = (unsigned short*)alloc(SZ_W);
    unsigned short* whh  = (unsigned short*)alloc(SZ_W);
    float*          bias = (float*)alloc(SZ_BIAS);
    unsigned short* hbuf = (unsigned short*)alloc(SZ_HBUF);
    unsigned*       bar  = (unsigned*)alloc(SZ_BAR);
    float* sums   = (float*)xg;
    float* counts = sums + (size_t)VOCAB * DD;

    hipMemsetAsync(sums, 0, SZ_SUMS, stream);
    hipMemsetAsync(bar, 0, SZ_BAR, stream);
    seg_scatter<<<ROWS, 256, 0, stream>>>(batch, hidden, sums, counts);
    build_x<<<ROWS, 256, 0, stream>>>(batch, hidden, sums, counts, xbf);
    conv_bias_perm<<<(NB2 + 255) / 256, 256, 0, stream>>>(b_ih_f, b_hh_f, b_ih_b, b_hh_b, bias);
    conv_w_perm<<<(unsigned)((nWHH + 255) / 256), 256, 0, stream>>>(w_hh_f, whh, DD);
    conv_w_perm<<<(unsigned)((nWHH + 255) / 256), 256, 0, stream>>>(w_hh_b, whh + (size_t)G4 * DD, DD);

    for (int dir = 0; dir < 2; dir++) {
      conv_w_perm<<<(unsigned)((nWIH + 255) / 256), 256, 0, stream>>>(dir ? w_ih_b : w_ih_f, wih, IN2);
      {
        dim3 grid(ROWS / 256, G4 / 256, 1);
        gemm_bt256<<<grid, 512, 0, stream>>>(xbf, IN2, wih, IN2, xg, G4,
                                             bias + (size_t)dir * G4, IN2);
      }
      hipMemsetAsync(hbuf, 0, SZ_HBUF, stream);
      lstm_persist<0><<<96, 512, 0, stream>>>(xg, G4, whh, hbuf, outc, bar, dir, 1);
    }
    final_linear<<<ROWS / 2, 256, 0, stream>>>(outc, lin_w, lin_b, out);
  }
}